// Round 4
// baseline (802.905 us; speedup 1.0000x reference)
//
#include <hip/hip_runtime.h>
#include <math.h>

// ============================ problem constants ============================
#define NB    128
#define NS    40
#define NW    50
#define ED    200   // = 2*HW = 2*HS
#define NHW   100
#define FEAT  200
#define NC    10
#define VOCABM1 99999
#define KL2E  1.4426950408889634f

// ============================ ws memory map (bytes) ========================
// v5 blobs are in FRAGMENT order for direct coalesced global->VGPR loads:
//   21 fragments x 1024 B; fragment f = kc*3 + g; lane l's 16 B at
//   f*1024 + l*16 holds 8 bf16 = W[row g*16+(l&15)][K kc*32+(l>>4)*8 ..+8],
//   zero-padded (genuine bf16 zeros) for row/K out of range.
// GRU consts at 21504: bias[sect][16] f32 (sect: bR',bZ',bN2,hN2), 256 B.
// Attn consts at 21504: ab2[48] f32; at 21696: cxn[48] f32.
// 38 blobs (word 0..18, sent 19..37), stride 22,016 B. Total 836,608.
#define BBn      22016ull
#define OFF_SV   846336ull             // svec [5120][200] bf16 = 2,048,000
#define OFF_DV   2894336ull            // dvec [128][200] bf16 = 51,200
#define WS_NEED  4194304ull            // covers fp32 fallback's svec too

// LDS: H only (wave-private rows) -> no in-loop barriers, 3 blocks/CU.
#define HST    400                     // Hsh row stride (bank-stride 4)
#define HBYTES 20000                   // per-group H: 50 rows x 400 B

// ============================ helpers ======================================
typedef short bf16x8 __attribute__((ext_vector_type(8)));
typedef float f32x4  __attribute__((ext_vector_type(4)));
typedef unsigned u32x4 __attribute__((ext_vector_type(4)));

__device__ __forceinline__ unsigned short f2bf(float f) {
    unsigned int u = __float_as_uint(f);
    u += 0x7fffu + ((u >> 16) & 1u);          // RNE
    return (unsigned short)(u >> 16);
}
__device__ __forceinline__ float bf2f(short s) {
    return __uint_as_float(((unsigned int)(unsigned short)s) << 16);
}
__device__ __forceinline__ unsigned pk2(float a, float b) {
    return (unsigned)f2bf(a) | ((unsigned)f2bf(b) << 16);
}
__device__ __forceinline__ float frcp(float x) { return __builtin_amdgcn_rcpf(x); }
#if __has_builtin(__builtin_amdgcn_exp2f)
__device__ __forceinline__ float fexp2(float x){ return __builtin_amdgcn_exp2f(x); }
#else
__device__ __forceinline__ float fexp2(float x){ return exp2f(x); }
#endif
__device__ __forceinline__ float fsig(float x) { return frcp(1.f + __expf(-x)); }
__device__ __forceinline__ float ftanh(float x){ return 1.f - 2.f*frcp(1.f + __expf(2.f*x)); }

// HW packed f32->bf16 (RNE), 1 inst per 2 values
__device__ __forceinline__ unsigned cvtpk(float lo, float hi) {
    unsigned r;
    asm("v_cvt_pk_bf16_f32 %0, %1, %2" : "=v"(r) : "v"(lo), "v"(hi));
    return r;
}
__device__ __forceinline__ bf16x8 pack8(float4 a, float4 b) {
    u32x4 t;
    t[0] = cvtpk(a.x, a.y); t[1] = cvtpk(a.z, a.w);
    t[2] = cvtpk(b.x, b.y); t[3] = cvtpk(b.z, b.w);
    return __builtin_bit_cast(bf16x8, t);
}

// ============================ P1: weight packing ===========================
// One block per blob (38). Every byte of the fragment region is written
// (value or zero), so no memset pass is needed.
__global__ void pack_kernel(
    const float* __restrict__ wWf, const float* __restrict__ wbif, const float* __restrict__ wbhf,
    const float* __restrict__ wWb, const float* __restrict__ wbib, const float* __restrict__ wbhb,
    const float* __restrict__ waW, const float* __restrict__ wab, const float* __restrict__ wactx,
    const float* __restrict__ sWf, const float* __restrict__ sbif, const float* __restrict__ sbhf,
    const float* __restrict__ sWb, const float* __restrict__ sbib, const float* __restrict__ sbhb,
    const float* __restrict__ saW, const float* __restrict__ sab, const float* __restrict__ sactx,
    char* __restrict__ ws)
{
    const int b = blockIdx.x, tid = threadIdx.x;
    const bool word = b < 19;
    const int lb = word ? b : b - 19;
    char* blob = ws + (size_t)b * BBn;

    if (lb < 14) {
        const int dir = lb / 7, c = lb % 7;
        const float* W   = word ? (dir ? wWb : wWf) : (dir ? sWb : sWf);
        const float* bih = word ? (dir ? wbib : wbif) : (dir ? sbib : sbif);
        const float* bhh = word ? (dir ? wbhb : wbhf) : (dir ? sbhb : sbhf);
        for (int e = tid; e < 21 * 64; e += 256) {
            const int f = e >> 6, l = e & 63;
            const int g = f % 3, kc = f / 3;
            const int j = c * 16 + (l & 15);
            const int k0 = kc * 32 + (l >> 4) * 8;
            u32x4 out = {0u, 0u, 0u, 0u};
            if (j < NHW && k0 < 200) {
                const float* src = W + (size_t)(g * NHW + j) * ED + k0;
                out[0] = pk2(src[0], src[1]); out[1] = pk2(src[2], src[3]);
                out[2] = pk2(src[4], src[5]); out[3] = pk2(src[6], src[7]);
            }
            *(u32x4*)(blob + ((size_t)f << 10) + (size_t)l * 16) = out;
        }
        if (tid < 64) {
            const int sect = tid >> 4, idx = tid & 15, j = c * 16 + idx;
            float v = 0.f;
            if (j < NHW) {
                if (sect == 0)      v = -KL2E * (bih[j] + bhh[j]);
                else if (sect == 1) v =  KL2E * (bih[NHW + j] + bhh[NHW + j]);
                else if (sect == 2) v = 2.f * KL2E * bih[2 * NHW + j];
                else                v = 2.f * KL2E * bhh[2 * NHW + j];
            }
            *(float*)(blob + 21504 + sect * 64 + idx * 4) = v;
        }
    } else {
        const int cb = lb - 14;
        const float* W  = word ? waW : saW;
        const float* ab = word ? wab : sab;
        const float* cx = word ? wactx : sactx;
        for (int e = tid; e < 21 * 64; e += 256) {
            const int f = e >> 6, l = e & 63;
            const int g = f % 3, kc = f / 3;
            const int d = cb * 48 + g * 16 + (l & 15);
            const int k0 = kc * 32 + (l >> 4) * 8;
            u32x4 out = {0u, 0u, 0u, 0u};
            if (d < FEAT && k0 < 200) {
                const float* src = W + (size_t)d * FEAT + k0;
                out[0] = pk2(src[0], src[1]); out[1] = pk2(src[2], src[3]);
                out[2] = pk2(src[4], src[5]); out[3] = pk2(src[6], src[7]);
            }
            *(u32x4*)(blob + ((size_t)f << 10) + (size_t)l * 16) = out;
        }
        if (tid < 48) {
            const int d = cb * 48 + tid;
            float ab2 = 0.f, cxn = 0.f;
            if (d < FEAT) { ab2 = 2.f * KL2E * ab[d]; cxn = -2.f * cx[d]; }
            *(float*)(blob + 21504 + tid * 4) = ab2;
            *(float*)(blob + 21696 + tid * 4) = cxn;
        }
    }
}

// ============================ fused HAN stage kernel =======================
// v5: NG groups/block, 2 waves/group (Mt=2). B-weights read DIRECTLY from
// global (L2-resident fragment-order blobs, coalesced dwordx4) -> no LDS
// staging, no double-buffer, and NO barriers in the 19-stage loop (H rows
// are wave-private; same-wave LDS ordering via lgkmcnt). LDS = H only
// (~41 KB for NG=2) -> 3 blocks/CU at launch_bounds(.,3) = 12 waves/CU,
// all free-running. One __syncthreads after the loop protects the
// sc/al/part alias of H rows 0..5 for the cross-wave softmax/pool exchange.
template<bool WORD, int NG>
__global__ __launch_bounds__(NG * 128, 3) void han_kernel(
    const int* __restrict__ xtok,
    const void* __restrict__ Ain,
    const char* __restrict__ pk,     // 19 blobs, stride BBn (GRU 0..13, attn 14..18)
    const int nvalid,                // 50 / 40
    unsigned short* __restrict__ Out)
{
    __shared__ __align__(16) char Hsh[NG * HBYTES];

    const int tid  = threadIdx.x;
    const int lane = tid & 63, wv = tid >> 6;
    const int sent = wv >> 1, half = wv & 1;
    const int ln15 = lane & 15, q = lane >> 4;
    const long g   = (long)blockIdx.x * NG + sent;
    char* Hme = Hsh + (size_t)sent * HBYTES;
    // post-loop alias region (rows 0..5 of this group's H, dead by then)
    float* sc_sh = (float*)Hme;                  // 64 f32
    float* al_sh = (float*)(Hme + 256);          // 64 f32
    float* part  = (float*)(Hme + 512);          // [2][224] f32

    // ---- A fragments ----
    bf16x8 af[2][7];
    if (WORD) {
        const float* emb = (const float*)Ain;
        #pragma unroll
        for (int Mt = 0; Mt < 2; ++Mt) {
            const int item = half * 32 + Mt * 16 + ln15;
            int tok = VOCABM1;                       // padding row: all zeros
            if (item < nvalid) tok = xtok[g * nvalid + item];
            const float4* rp = (const float4*)(emb + (long)tok * ED);
            #pragma unroll
            for (int kc = 0; kc < 6; ++kc)
                af[Mt][kc] = pack8(rp[kc * 8 + q * 2], rp[kc * 8 + q * 2 + 1]);
            af[Mt][6] = (q == 0) ? pack8(rp[48], rp[49]) : (bf16x8)(short)0;
        }
    } else {
        const char* sv = (const char*)Ain;
        #pragma unroll
        for (int Mt = 0; Mt < 2; ++Mt) {
            const int item = half * 32 + Mt * 16 + ln15;
            const int ic = item < nvalid ? item : nvalid - 1;
            const char* rp = sv + (g * nvalid + ic) * 400;
            #pragma unroll
            for (int kc = 0; kc < 7; ++kc) {
                bf16x8 v = (bf16x8)(short)0;
                if (item < nvalid && (kc < 6 || q == 0))
                    v = *(const bf16x8*)(rp + kc * 64 + q * 16);
                af[Mt][kc] = v;
            }
        }
    }

    bf16x8 hf[2][7];
    float sacc[2][4] = {{0.f}};

    #pragma unroll 1
    for (int s = 0; s < 19; ++s) {
        const char* blob = pk + (size_t)s * BBn;
        const char* fb   = blob + (size_t)lane * 16;   // per-lane fragment base

        if (s < 14) {
            // ---- GRU chunk: units [cc*16, +16) of direction dir ----
            f32x4 a0[2] = {}, a1[2] = {}, a2[2] = {};
            #pragma unroll
            for (int kc = 0; kc < 7; ++kc) {
                const bf16x8 b0 = *(const bf16x8*)(fb + ((kc * 3 + 0) << 10));
                const bf16x8 b1 = *(const bf16x8*)(fb + ((kc * 3 + 1) << 10));
                const bf16x8 b2 = *(const bf16x8*)(fb + ((kc * 3 + 2) << 10));
                #pragma unroll
                for (int Mt = 0; Mt < 2; ++Mt) {
                    a0[Mt] = __builtin_amdgcn_mfma_f32_16x16x32_bf16(b0, af[Mt][kc], a0[Mt], 0, 0, 0);
                    a1[Mt] = __builtin_amdgcn_mfma_f32_16x16x32_bf16(b1, af[Mt][kc], a1[Mt], 0, 0, 0);
                    a2[Mt] = __builtin_amdgcn_mfma_f32_16x16x32_bf16(b2, af[Mt][kc], a2[Mt], 0, 0, 0);
                }
            }
            const int dir = s / 7, cc = s - dir * 7;
            if (cc * 16 + q * 4 < NHW) {
                const f32x4 bR = *(const f32x4*)(blob + 21504 +   0 + q * 16);
                const f32x4 bZ = *(const f32x4*)(blob + 21504 +  64 + q * 16);
                const f32x4 bN = *(const f32x4*)(blob + 21504 + 128 + q * 16);
                const f32x4 hN = *(const f32x4*)(blob + 21504 + 192 + q * 16);
                const int ub = dir * NHW + cc * 16 + q * 4;
                #pragma unroll
                for (int Mt = 0; Mt < 2; ++Mt) {
                    const int item = half * 32 + Mt * 16 + ln15;
                    float h[4];
                    #pragma unroll
                    for (int rg = 0; rg < 4; ++rg) {
                        const float r  = frcp(1.f + fexp2(fmaf(a0[Mt][rg], -KL2E, bR[rg])));
                        const float zc = frcp(1.f + fexp2(fmaf(a1[Mt][rg],  KL2E, bZ[rg])));
                        const float t  = frcp(1.f + fexp2(fmaf(a2[Mt][rg], 2.f * KL2E,
                                                  fmaf(r, hN[rg], bN[rg]))));
                        h[rg] = zc * (1.f - 2.f * t);
                    }
                    if (item < nvalid) {
                        uint2 o; o.x = cvtpk(h[0], h[1]); o.y = cvtpk(h[2], h[3]);
                        *(uint2*)(Hme + (size_t)item * HST + ub * 2) = o;
                    }
                }
            }
        } else {
            // ---- attention score chunk ----
            if (s == 14) {   // own-wave rows; same-wave ds ordering via lgkmcnt
                #pragma unroll
                for (int Mt = 0; Mt < 2; ++Mt) {
                    const int item = half * 32 + Mt * 16 + ln15;
                    #pragma unroll
                    for (int kc = 0; kc < 7; ++kc) {
                        bf16x8 v = (bf16x8)(short)0;
                        if (item < nvalid && (kc < 6 || q == 0))
                            v = *(const bf16x8*)(Hme + (size_t)item * HST + kc * 64 + q * 16);
                        hf[Mt][kc] = v;
                    }
                }
            }
            f32x4 ac[2][3] = {};
            #pragma unroll
            for (int kc = 0; kc < 7; ++kc) {
                const bf16x8 b0 = *(const bf16x8*)(fb + ((kc * 3 + 0) << 10));
                const bf16x8 b1 = *(const bf16x8*)(fb + ((kc * 3 + 1) << 10));
                const bf16x8 b2 = *(const bf16x8*)(fb + ((kc * 3 + 2) << 10));
                #pragma unroll
                for (int Mt = 0; Mt < 2; ++Mt) {
                    ac[Mt][0] = __builtin_amdgcn_mfma_f32_16x16x32_bf16(hf[Mt][kc], b0, ac[Mt][0], 0, 0, 0);
                    ac[Mt][1] = __builtin_amdgcn_mfma_f32_16x16x32_bf16(hf[Mt][kc], b1, ac[Mt][1], 0, 0, 0);
                    ac[Mt][2] = __builtin_amdgcn_mfma_f32_16x16x32_bf16(hf[Mt][kc], b2, ac[Mt][2], 0, 0, 0);
                }
            }
            // tanh(u)·cx folded: sacc += cx2n / (1 + exp2(2K·acc + ab2))
            #pragma unroll
            for (int Nt = 0; Nt < 3; ++Nt) {
                const float ab2 = *(const float*)(blob + 21504 + (Nt * 16 + ln15) * 4);
                const float cxn = *(const float*)(blob + 21696 + (Nt * 16 + ln15) * 4);
                #pragma unroll
                for (int Mt = 0; Mt < 2; ++Mt)
                    #pragma unroll
                    for (int rg = 0; rg < 4; ++rg) {
                        const float u = frcp(1.f + fexp2(fmaf(ac[Mt][Nt][rg], 2.f * KL2E, ab2)));
                        sacc[Mt][rg] = fmaf(u, cxn, sacc[Mt][rg]);
                    }
            }
        }
        // no barrier: H is wave-private, B comes from global
    }

    // ---- reduce scores over the 16 d-lanes ----
    #pragma unroll
    for (int Mt = 0; Mt < 2; ++Mt)
        #pragma unroll
        for (int rg = 0; rg < 4; ++rg) {
            float v = sacc[Mt][rg];
            v += __shfl_xor(v, 1); v += __shfl_xor(v, 2);
            v += __shfl_xor(v, 4); v += __shfl_xor(v, 8);
            sacc[Mt][rg] = v;
        }

    // All waves are past their hf loads only after this barrier -> the
    // sc/al/part alias of H rows 0..5 becomes safe.
    __syncthreads();

    if (ln15 == 0) {
        #pragma unroll
        for (int Mt = 0; Mt < 2; ++Mt)
            #pragma unroll
            for (int rg = 0; rg < 4; ++rg)
                sc_sh[half * 32 + Mt * 16 + q * 4 + rg] = sacc[Mt][rg];
    }
    __syncthreads();

    // ---- per-group softmax over 64 padded rows (exp2-scaled) ----
    {
        const float sv0 = (lane < nvalid) ? sc_sh[lane] : -1e30f;
        float m = sv0;
        m = fmaxf(m, __shfl_xor(m, 1));  m = fmaxf(m, __shfl_xor(m, 2));
        m = fmaxf(m, __shfl_xor(m, 4));  m = fmaxf(m, __shfl_xor(m, 8));
        m = fmaxf(m, __shfl_xor(m, 16)); m = fmaxf(m, __shfl_xor(m, 32));
        const float e = (lane < nvalid) ? fexp2((sv0 - m) * KL2E) : 0.f;
        float ss = e;
        ss += __shfl_xor(ss, 1);  ss += __shfl_xor(ss, 2);
        ss += __shfl_xor(ss, 4);  ss += __shfl_xor(ss, 8);
        ss += __shfl_xor(ss, 16); ss += __shfl_xor(ss, 32);
        if (half == 0) al_sh[lane] = e * frcp(ss);
    }
    __syncthreads();

    // ---- pooling straight from hf fragments ----
    {
        const float aM0 = al_sh[half * 32 + ln15];
        const float aM1 = al_sh[half * 32 + 16 + ln15];
        #pragma unroll
        for (int kc = 0; kc < 7; ++kc) {
            float p[8];
            #pragma unroll
            for (int j = 0; j < 8; ++j)
                p[j] = aM0 * bf2f(hf[0][kc][j]) + aM1 * bf2f(hf[1][kc][j]);
            #pragma unroll
            for (int j = 0; j < 8; ++j) {
                p[j] += __shfl_xor(p[j], 1); p[j] += __shfl_xor(p[j], 2);
                p[j] += __shfl_xor(p[j], 4); p[j] += __shfl_xor(p[j], 8);
            }
            if (ln15 == 0) {
                float* dst = part + (size_t)half * 224 + kc * 32 + q * 8;
                f32x4 v0 = {p[0], p[1], p[2], p[3]};
                f32x4 v1 = {p[4], p[5], p[6], p[7]};
                *(f32x4*)dst = v0; *(f32x4*)(dst + 4) = v1;
            }
        }
    }
    __syncthreads();

    // ---- combine halves, write pooled bf16 rows ----
    if (tid < NG * 50) {
        const int sl = tid / 50, i = tid - sl * 50;     // i*4 = k0 < 200
        const float* pg = (const float*)(Hsh + (size_t)sl * HBYTES + 512);
        const float* pa = pg;
        const float* pb = pg + 224;
        uint2 o;
        o.x = cvtpk(pa[i * 4 + 0] + pb[i * 4 + 0], pa[i * 4 + 1] + pb[i * 4 + 1]);
        o.y = cvtpk(pa[i * 4 + 2] + pb[i * 4 + 2], pa[i * 4 + 3] + pb[i * 4 + 3]);
        *(uint2*)(Out + ((long)blockIdx.x * NG + sl) * 200 + i * 4) = o;
    }
}

// ============================ classifier + log_softmax =====================
__global__ void cls_kernel(const unsigned short* __restrict__ dvec,
                           const float* __restrict__ fcW, const float* __restrict__ fcb,
                           float* __restrict__ out)
{
    const int doc = blockIdx.x, lane = threadIdx.x;  // 64 threads
    const int c = lane & 15, part = lane >> 4;
    const int cs = (c < NC) ? c : 0;
    float acc = (part == 0 && c < NC) ? fcb[c] : 0.f;
    for (int i = 0; i < 50; ++i) {
        const int k = part * 50 + i;
        const float a = bf2f((short)dvec[(size_t)doc * 200 + k]);
        acc += a * ((c < NC) ? fcW[(size_t)cs * 200 + k] : 0.f);
    }
    acc += __shfl_xor(acc, 16); acc += __shfl_xor(acc, 32);
    const float lg = (c < NC) ? acc : -1e30f;
    float m = lg;
    m = fmaxf(m, __shfl_xor(m, 1)); m = fmaxf(m, __shfl_xor(m, 2));
    m = fmaxf(m, __shfl_xor(m, 4)); m = fmaxf(m, __shfl_xor(m, 8));
    const float e = (c < NC) ? __expf(lg - m) : 0.f;
    float ss = e;
    ss += __shfl_xor(ss, 1); ss += __shfl_xor(ss, 2);
    ss += __shfl_xor(ss, 4); ss += __shfl_xor(ss, 8);
    const float lse = m + __logf(ss);
    if (lane < NC) out[(size_t)doc * NC + lane] = lg - lse;
}

// ======================================================================
// Fallback fp32 path — used only if ws_size < WS_NEED.
// ======================================================================
template<int NWRD, int WT>
__device__ __forceinline__ void encode_block(
    float* __restrict__ e_sh, float* __restrict__ h_sh, float* __restrict__ sc_sh,
    const float* __restrict__ Wf, const float* __restrict__ bihf, const float* __restrict__ bhhf,
    const float* __restrict__ Wb, const float* __restrict__ bihb, const float* __restrict__ bhhb,
    const float* __restrict__ aW, const float* __restrict__ ab, const float* __restrict__ actx,
    int tid)
{
    constexpr int WG = NWRD / WT;
    for (int item = tid; item < FEAT * WG; item += 256) {
        const int unit = item % FEAT, wg = item / FEAT;
        const int dir = unit / NHW, j = unit - dir * NHW;
        const float* Wd  = dir ? Wb : Wf;
        const float* bih = dir ? bihb : bihf;
        const float* bhh = dir ? bhhb : bhhf;
        const float4* rowR = (const float4*)(Wd + (size_t)j * ED);
        const float4* rowZ = (const float4*)(Wd + (size_t)(NHW + j) * ED);
        const float4* rowN = (const float4*)(Wd + (size_t)(2 * NHW + j) * ED);
        float aR[WT], aZ[WT], aN[WT];
        #pragma unroll
        for (int t = 0; t < WT; ++t) { aR[t] = 0.f; aZ[t] = 0.f; aN[t] = 0.f; }
        const int w0 = wg * WT;
        #pragma unroll 1
        for (int k4 = 0; k4 < ED / 4; ++k4) {
            const float4 wr = rowR[k4], wz = rowZ[k4], wn = rowN[k4];
            #pragma unroll
            for (int t = 0; t < WT; ++t) {
                const float4 e = *(const float4*)(e_sh + (w0 + t) * ED + k4 * 4);
                aR[t] += wr.x*e.x + wr.y*e.y + wr.z*e.z + wr.w*e.w;
                aZ[t] += wz.x*e.x + wz.y*e.y + wz.z*e.z + wz.w*e.w;
                aN[t] += wn.x*e.x + wn.y*e.y + wn.z*e.z + wn.w*e.w;
            }
        }
        const float bR = bih[j] + bhh[j], bZ = bih[NHW+j] + bhh[NHW+j];
        const float bN = bih[2*NHW+j], hN = bhh[2*NHW+j];
        #pragma unroll
        for (int t = 0; t < WT; ++t) {
            const float r = fsig(aR[t] + bR), z = fsig(aZ[t] + bZ);
            const float n = ftanh(aN[t] + bN + r * hN);
            h_sh[(w0 + t) * FEAT + unit] = (1.f - z) * n;
        }
    }
    __syncthreads();
    for (int item = tid; item < FEAT * WG; item += 256) {
        const int d = item % FEAT, wg = item / FEAT;
        const float4* row = (const float4*)(aW + (size_t)d * FEAT);
        float acc[WT];
        #pragma unroll
        for (int t = 0; t < WT; ++t) acc[t] = 0.f;
        const int w0 = wg * WT;
        #pragma unroll 1
        for (int k4 = 0; k4 < FEAT / 4; ++k4) {
            const float4 wv = row[k4];
            #pragma unroll
            for (int t = 0; t < WT; ++t) {
                const float4 h = *(const float4*)(h_sh + (w0 + t) * FEAT + k4 * 4);
                acc[t] += wv.x*h.x + wv.y*h.y + wv.z*h.z + wv.w*h.w;
            }
        }
        const float bb = ab[d], cc = actx[d];
        #pragma unroll
        for (int t = 0; t < WT; ++t)
            e_sh[d * NWRD + (w0 + t)] = ftanh(acc[t] + bb) * cc;
    }
    __syncthreads();
    if (tid < NWRD) {
        float s = 0.f;
        for (int d = 0; d < FEAT; ++d) s += e_sh[d * NWRD + tid];
        sc_sh[tid] = s;
    }
    __syncthreads();
    if (tid == 0) {
        float m = -1e30f;
        for (int w = 0; w < NWRD; ++w) m = fmaxf(m, sc_sh[w]);
        float s = 0.f;
        for (int w = 0; w < NWRD; ++w) { const float ev = __expf(sc_sh[w] - m); sc_sh[w] = ev; s += ev; }
        const float inv = 1.f / s;
        for (int w = 0; w < NWRD; ++w) sc_sh[w] *= inv;
    }
    __syncthreads();
}

__global__ __launch_bounds__(256) void word_kernel_f32(
    const int* __restrict__ x, const float* __restrict__ emb,
    const float* __restrict__ Wf, const float* __restrict__ bihf, const float* __restrict__ bhhf,
    const float* __restrict__ Wb, const float* __restrict__ bihb, const float* __restrict__ bhhb,
    const float* __restrict__ waW, const float* __restrict__ wab, const float* __restrict__ wactx,
    float* __restrict__ svec)
{
    __shared__ __align__(16) float e_sh[NW * ED];
    __shared__ __align__(16) float h_sh[NW * FEAT];
    __shared__ float sc_sh[NW];
    const int sent = blockIdx.x, tid = threadIdx.x;
    const int* xr = x + (size_t)sent * NW;
    for (int i = tid * 4; i < NW * ED; i += 256 * 4) {
        const int w = i / ED, k = i - w * ED;
        *(float4*)(e_sh + i) = *(const float4*)(emb + (size_t)xr[w] * ED + k);
    }
    __syncthreads();
    encode_block<NW, 25>(e_sh, h_sh, sc_sh, Wf, bihf, bhhf, Wb, bihb, bhhb, waW, wab, wactx, tid);
    if (tid < FEAT) {
        float a = 0.f;
        #pragma unroll 1
        for (int w = 0; w < NW; ++w) a += sc_sh[w] * h_sh[w * FEAT + tid];
        svec[(size_t)sent * FEAT + tid] = a;
    }
}

__global__ __launch_bounds__(256) void sent_kernel_f32(
    const float* __restrict__ svec,
    const float* __restrict__ Wf, const float* __restrict__ bihf, const float* __restrict__ bhhf,
    const float* __restrict__ Wb, const float* __restrict__ bihb, const float* __restrict__ bhhb,
    const float* __restrict__ saW, const float* __restrict__ sab, const float* __restrict__ sactx,
    const float* __restrict__ fcW, const float* __restrict__ fcb,
    float* __restrict__ out)
{
    __shared__ __align__(16) float e_sh[NS * ED];
    __shared__ __align__(16) float h_sh[NS * FEAT];
    __shared__ float sc_sh[NS];
    __shared__ float dvec_sh[FEAT];
    __shared__ float logit_sh[NC];
    __shared__ float lse_sh;
    const int b = blockIdx.x, tid = threadIdx.x;
    const float* src = svec + (size_t)b * NS * FEAT;
    for (int i = tid * 4; i < NS * FEAT; i += 256 * 4)
        *(float4*)(e_sh + i) = *(const float4*)(src + i);
    __syncthreads();
    encode_block<NS, 20>(e_sh, h_sh, sc_sh, Wf, bihf, bhhf, Wb, bihb, bhhb, saW, sab, sactx, tid);
    if (tid < FEAT) {
        float a = 0.f;
        #pragma unroll 1
        for (int s = 0; s < NS; ++s) a += sc_sh[s] * h_sh[s * FEAT + tid];
        dvec_sh[tid] = a;
    }
    __syncthreads();
    if (tid < NC) {
        float a = fcb[tid];
        const float* row = fcW + (size_t)tid * FEAT;
        for (int k = 0; k < FEAT; ++k) a += row[k] * dvec_sh[k];
        logit_sh[tid] = a;
    }
    __syncthreads();
    if (tid == 0) {
        float m = -1e30f;
        for (int c = 0; c < NC; ++c) m = fmaxf(m, logit_sh[c]);
        float s = 0.f;
        for (int c = 0; c < NC; ++c) s += __expf(logit_sh[c] - m);
        lse_sh = m + logf(s);
    }
    __syncthreads();
    if (tid < NC) out[(size_t)b * NC + tid] = logit_sh[tid] - lse_sh;
}

// ============================ launch =======================================
extern "C" void kernel_launch(void* const* d_in, const int* in_sizes, int n_in,
                              void* d_out, int out_size, void* d_ws, size_t ws_size,
                              hipStream_t stream)
{
    const int*   x     = (const int*)d_in[0];
    const float* emb   = (const float*)d_in[1];
    const float* wWf   = (const float*)d_in[2];
    const float* wbif  = (const float*)d_in[3];
    const float* wbhf  = (const float*)d_in[4];
    const float* wWb   = (const float*)d_in[5];
    const float* wbib  = (const float*)d_in[6];
    const float* wbhb  = (const float*)d_in[7];
    const float* waW   = (const float*)d_in[8];
    const float* wab   = (const float*)d_in[9];
    const float* wactx = (const float*)d_in[10];
    const float* sWf   = (const float*)d_in[11];
    const float* sbif  = (const float*)d_in[12];
    const float* sbhf  = (const float*)d_in[13];
    const float* sWb   = (const float*)d_in[14];
    const float* sbib  = (const float*)d_in[15];
    const float* sbhb  = (const float*)d_in[16];
    const float* saW   = (const float*)d_in[17];
    const float* sab   = (const float*)d_in[18];
    const float* sactx = (const float*)d_in[19];
    const float* fcW   = (const float*)d_in[20];
    const float* fcb   = (const float*)d_in[21];
    float* out = (float*)d_out;

    if (ws_size < WS_NEED) {
        float* svec = (float*)d_ws;
        word_kernel_f32<<<NB * NS, 256, 0, stream>>>(
            x, emb, wWf, wbif, wbhf, wWb, wbib, wbhb, waW, wab, wactx, svec);
        sent_kernel_f32<<<NB, 256, 0, stream>>>(
            svec, sWf, sbif, sbhf, sWb, sbib, sbhb, saW, sab, sactx, fcW, fcb, out);
        return;
    }

    char* ws = (char*)d_ws;
    unsigned short* svec = (unsigned short*)(ws + OFF_SV);
    unsigned short* dvec = (unsigned short*)(ws + OFF_DV);

    pack_kernel<<<38, 256, 0, stream>>>(
        wWf, wbif, wbhf, wWb, wbib, wbhb, waW, wab, wactx,
        sWf, sbif, sbhf, sWb, sbib, sbhb, saW, sab, sactx, ws);

    // word stage: 5120 sentences / 2 per block (256 thr)
    han_kernel<true, 2><<<NB * NS / 2, 256, 0, stream>>>(
        x, emb, ws, NW, svec);

    // sentence stage: 128 docs / 1 per block (128 thr)
    han_kernel<false, 1><<<NB, 128, 0, stream>>>(
        nullptr, svec, ws + 19ull * BBn, NS, dvec);

    cls_kernel<<<NB, 64, 0, stream>>>(dvec, fcW, fcb, out);
}

// Round 5
// 413.325 us; speedup vs baseline: 1.9426x; 1.9426x over previous
//
#include <hip/hip_runtime.h>
#include <math.h>

// ============================ problem constants ============================
#define NB    128
#define NS    40
#define NW    50
#define ED    200   // = 2*HW = 2*HS
#define NHW   100
#define FEAT  200
#define NC    10
#define VOCABM1 99999
#define KL2E  1.4426950408889634f

// ============================ ws memory map (bytes) ========================
// v6 blobs, fragment order for lane-linear LDS reads after staging:
//   kc=0..5: 18 fragments x 1024 B at f*1024, f = kc*3 + g; lane l's 16 B =
//     8 bf16 of W[row g*16+(l&15)][k = kc*32+(l>>4)*8 ..+8] (zeros padded).
//   kc=6 compact: 3 x 256 B at 18432 + g*256 + ln*16 = rows ln, k=192..200.
//     (q>=1 lanes broadcast-read the q==0 data; matching A/hf elems are 0.)
//   consts at 19200: GRU: bias[4 sect][16] f32 (bR',bZ',bN2,hN2), 256 B.
//                    attn: ab2[48] f32 at 19200; cxn[48] f32 at 19392.
// Blob stride 19,712 B; 38 blobs (word 0..18, sent 19..37) = 749,056 B.
#define BBn      19712ull
#define OFF_SV   846336ull             // svec [5120][200] bf16 = 2,048,000
#define OFF_DV   2894336ull            // dvec [128][200] bf16 = 51,200
#define WS_NEED  4194304ull            // covers fp32 fallback's svec too

// LDS: 2 staging slots + 2 wave-private H -> 79,424 B -> 2 blocks/CU.
#define SLOT   19712
#define HST    400                     // Hsh row stride (bank-stride 4)
#define HBYTES 20000                   // per-group H: 50 rows x 400 B

// ============================ helpers ======================================
typedef short bf16x8 __attribute__((ext_vector_type(8)));
typedef float f32x4  __attribute__((ext_vector_type(4)));
typedef unsigned u32x4 __attribute__((ext_vector_type(4)));

__device__ __forceinline__ unsigned short f2bf(float f) {
    unsigned int u = __float_as_uint(f);
    u += 0x7fffu + ((u >> 16) & 1u);          // RNE
    return (unsigned short)(u >> 16);
}
__device__ __forceinline__ float bf2f(short s) {
    return __uint_as_float(((unsigned int)(unsigned short)s) << 16);
}
__device__ __forceinline__ unsigned pk2(float a, float b) {
    return (unsigned)f2bf(a) | ((unsigned)f2bf(b) << 16);
}
__device__ __forceinline__ float frcp(float x) { return __builtin_amdgcn_rcpf(x); }
#if __has_builtin(__builtin_amdgcn_exp2f)
__device__ __forceinline__ float fexp2(float x){ return __builtin_amdgcn_exp2f(x); }
#else
__device__ __forceinline__ float fexp2(float x){ return exp2f(x); }
#endif
__device__ __forceinline__ float fsig(float x) { return frcp(1.f + __expf(-x)); }
__device__ __forceinline__ float ftanh(float x){ return 1.f - 2.f*frcp(1.f + __expf(2.f*x)); }

// HW packed f32->bf16 (RNE), 1 inst per 2 values
__device__ __forceinline__ unsigned cvtpk(float lo, float hi) {
    unsigned r;
    asm("v_cvt_pk_bf16_f32 %0, %1, %2" : "=v"(r) : "v"(lo), "v"(hi));
    return r;
}
__device__ __forceinline__ bf16x8 pack8(float4 a, float4 b) {
    u32x4 t;
    t[0] = cvtpk(a.x, a.y); t[1] = cvtpk(a.z, a.w);
    t[2] = cvtpk(b.x, b.y); t[3] = cvtpk(b.z, b.w);
    return __builtin_bit_cast(bf16x8, t);
}

// async global->LDS, 16B per lane; LDS dst = wave-uniform base + lane*16.
__device__ __forceinline__ void gld16(const void* g, void* l) {
    __builtin_amdgcn_global_load_lds(
        (const __attribute__((address_space(1))) void*)g,
        (__attribute__((address_space(3))) void*)l, 16, 0, 0);
}

// stage one 19,712-B blob with 128 threads: 1232 16B units (9/thr + 80 extra)
__device__ __forceinline__ void stageBlob(char* __restrict__ dst,
                                          const char* __restrict__ src, int tid)
{
    #pragma unroll
    for (int u = 0; u < 9; ++u)
        gld16(src + (size_t)(u * 128 + tid) * 16, dst + (size_t)(u * 128 + tid) * 16);
    if (tid < 80)
        gld16(src + (size_t)(1152 + tid) * 16, dst + (size_t)(1152 + tid) * 16);
}

// ============================ P1: weight packing ===========================
// One block per blob (38). Every fragment byte is written (value or zero).
__global__ void pack_kernel(
    const float* __restrict__ wWf, const float* __restrict__ wbif, const float* __restrict__ wbhf,
    const float* __restrict__ wWb, const float* __restrict__ wbib, const float* __restrict__ wbhb,
    const float* __restrict__ waW, const float* __restrict__ wab, const float* __restrict__ wactx,
    const float* __restrict__ sWf, const float* __restrict__ sbif, const float* __restrict__ sbhf,
    const float* __restrict__ sWb, const float* __restrict__ sbib, const float* __restrict__ sbhb,
    const float* __restrict__ saW, const float* __restrict__ sab, const float* __restrict__ sactx,
    char* __restrict__ ws)
{
    const int b = blockIdx.x, tid = threadIdx.x;
    const bool word = b < 19;
    const int lb = word ? b : b - 19;
    char* blob = ws + (size_t)b * BBn;

    if (lb < 14) {
        const int dir = lb / 7, c = lb % 7;
        const float* W   = word ? (dir ? wWb : wWf) : (dir ? sWb : sWf);
        const float* bih = word ? (dir ? wbib : wbif) : (dir ? sbib : sbif);
        const float* bhh = word ? (dir ? wbhb : wbhf) : (dir ? sbhb : sbhf);
        for (int e = tid; e < 18 * 64; e += 256) {           // kc 0..5 fragments
            const int f = e >> 6, l = e & 63;
            const int g = f % 3, kc = f / 3;
            const int j = c * 16 + (l & 15);
            const int k0 = kc * 32 + (l >> 4) * 8;           // <= 184 < 200
            u32x4 out = {0u, 0u, 0u, 0u};
            if (j < NHW) {
                const float* src = W + (size_t)(g * NHW + j) * ED + k0;
                out[0] = pk2(src[0], src[1]); out[1] = pk2(src[2], src[3]);
                out[2] = pk2(src[4], src[5]); out[3] = pk2(src[6], src[7]);
            }
            *(u32x4*)(blob + ((size_t)f << 10) + (size_t)l * 16) = out;
        }
        if (tid < 48) {                                      // kc 6 compact
            const int g = tid >> 4, ln = tid & 15;
            const int j = c * 16 + ln;
            u32x4 out = {0u, 0u, 0u, 0u};
            if (j < NHW) {
                const float* src = W + (size_t)(g * NHW + j) * ED + 192;
                out[0] = pk2(src[0], src[1]); out[1] = pk2(src[2], src[3]);
                out[2] = pk2(src[4], src[5]); out[3] = pk2(src[6], src[7]);
            }
            *(u32x4*)(blob + 18432 + g * 256 + ln * 16) = out;
        }
        if (tid < 64) {                                      // bias consts
            const int sect = tid >> 4, idx = tid & 15, j = c * 16 + idx;
            float v = 0.f;
            if (j < NHW) {
                if (sect == 0)      v = -KL2E * (bih[j] + bhh[j]);
                else if (sect == 1) v =  KL2E * (bih[NHW + j] + bhh[NHW + j]);
                else if (sect == 2) v = 2.f * KL2E * bih[2 * NHW + j];
                else                v = 2.f * KL2E * bhh[2 * NHW + j];
            }
            *(float*)(blob + 19200 + sect * 64 + idx * 4) = v;
        }
    } else {
        const int cb = lb - 14;
        const float* W  = word ? waW : saW;
        const float* ab = word ? wab : sab;
        const float* cx = word ? wactx : sactx;
        for (int e = tid; e < 18 * 64; e += 256) {
            const int f = e >> 6, l = e & 63;
            const int g = f % 3, kc = f / 3;
            const int d = cb * 48 + g * 16 + (l & 15);
            const int k0 = kc * 32 + (l >> 4) * 8;
            u32x4 out = {0u, 0u, 0u, 0u};
            if (d < FEAT) {
                const float* src = W + (size_t)d * FEAT + k0;
                out[0] = pk2(src[0], src[1]); out[1] = pk2(src[2], src[3]);
                out[2] = pk2(src[4], src[5]); out[3] = pk2(src[6], src[7]);
            }
            *(u32x4*)(blob + ((size_t)f << 10) + (size_t)l * 16) = out;
        }
        if (tid < 48) {
            const int g = tid >> 4, ln = tid & 15;
            const int d = cb * 48 + g * 16 + ln;
            u32x4 out = {0u, 0u, 0u, 0u};
            if (d < FEAT) {
                const float* src = W + (size_t)d * FEAT + 192;
                out[0] = pk2(src[0], src[1]); out[1] = pk2(src[2], src[3]);
                out[2] = pk2(src[4], src[5]); out[3] = pk2(src[6], src[7]);
            }
            *(u32x4*)(blob + 18432 + g * 256 + ln * 16) = out;
        }
        if (tid < 48) {
            const int d = cb * 48 + tid;
            float ab2 = 0.f, cxn = 0.f;
            if (d < FEAT) { ab2 = 2.f * KL2E * ab[d]; cxn = -2.f * cx[d]; }
            *(float*)(blob + 19200 + tid * 4) = ab2;
            *(float*)(blob + 19392 + tid * 4) = cxn;
        }
    }
}

// ============================ fused HAN stage kernel =======================
// v6: block = 2 groups x 1 wave (128 thr), Mt=4 (one wave owns all 64 item
// rows of its group). B-fragment LDS reads per MFMA halve vs v4; the whole
// softmax/pooling tail is wave-private (alpha redistribute via 256-B scratch
// in the dead H region) -> in-loop barriers only for the shared staging dbuf.
// Loop split GRU(0..13)/attn(14..18) so af/hf lifetimes don't overlap
// (register budget: ~210 peak, cap 256 via launch_bounds(128,2)).
// LDS 79,424 B -> 2 blocks/CU. kc==6 B reads hit the compact 768-B region
// (q>=1 lanes read q==0 data, harmless: matching A/hf elements are zero).
template<bool WORD>
__global__ __launch_bounds__(128, 2) void han_kernel(
    const int* __restrict__ xtok,
    const void* __restrict__ Ain,
    const char* __restrict__ pk,     // 19 blobs, stride BBn (GRU 0..13, attn 14..18)
    const int nvalid,                // 50 / 40
    unsigned short* __restrict__ Out)
{
    __shared__ __align__(16) char smem[2 * SLOT + 2 * HBYTES];   // 79,424
    char* bufs = smem;                           // 2 x 19,712
    char* Hsh  = smem + 2 * SLOT;                // [2][50][400]

    const int tid  = threadIdx.x;
    const int lane = tid & 63, wv = tid >> 6;    // wv = group (0/1)
    const int ln15 = lane & 15, q = lane >> 4;
    const long g   = (long)blockIdx.x * 2 + wv;
    char* Hme = Hsh + (size_t)wv * HBYTES;

    // ---- prologue staging: slot 0 = blob 0 ----
    stageBlob(bufs, pk, tid);

    // ---- A fragments (overlap staging latency): af[Mt][kc], Mt=0..3 ----
    bf16x8 af[4][7];
    if (WORD) {
        const float* emb = (const float*)Ain;
        #pragma unroll
        for (int Mt = 0; Mt < 4; ++Mt) {
            const int item = Mt * 16 + ln15;
            int tok = VOCABM1;                       // padding row: all zeros
            if (item < nvalid) tok = xtok[g * nvalid + item];
            const float4* rp = (const float4*)(emb + (long)tok * ED);
            #pragma unroll
            for (int kc = 0; kc < 6; ++kc)
                af[Mt][kc] = pack8(rp[kc * 8 + q * 2], rp[kc * 8 + q * 2 + 1]);
            af[Mt][6] = (q == 0) ? pack8(rp[48], rp[49]) : (bf16x8)(short)0;
        }
    } else {
        const char* sv = (const char*)Ain;
        #pragma unroll
        for (int Mt = 0; Mt < 4; ++Mt) {
            const int item = Mt * 16 + ln15;
            const int ic = item < nvalid ? item : nvalid - 1;
            const char* rp = sv + (g * nvalid + ic) * 400;
            #pragma unroll
            for (int kc = 0; kc < 7; ++kc) {
                bf16x8 v = (bf16x8)(short)0;
                if (item < nvalid && (kc < 6 || q == 0))
                    v = *(const bf16x8*)(rp + kc * 64 + q * 16);
                af[Mt][kc] = v;
            }
        }
    }

    __syncthreads();   // slot 0 resident

    // =================== GRU loop: s = 0..13 ===================
    #pragma unroll 1
    for (int s = 0; s < 14; ++s) {
        stageBlob(bufs + (size_t)((s + 1) & 1) * SLOT, pk + (size_t)(s + 1) * BBn, tid);
        const char* cur = bufs + (size_t)(s & 1) * SLOT;

        f32x4 a0[4] = {}, a1[4] = {}, a2[4] = {};
        #pragma unroll
        for (int kc = 0; kc < 7; ++kc) {
            bf16x8 b0, b1, b2;
            if (kc < 6) {
                b0 = *(const bf16x8*)(cur + ((kc * 3 + 0) << 10) + lane * 16);
                b1 = *(const bf16x8*)(cur + ((kc * 3 + 1) << 10) + lane * 16);
                b2 = *(const bf16x8*)(cur + ((kc * 3 + 2) << 10) + lane * 16);
            } else {     // compact region; q>=1 lanes broadcast q==0 data (A=0 there)
                b0 = *(const bf16x8*)(cur + 18432 +   0 + ln15 * 16);
                b1 = *(const bf16x8*)(cur + 18432 + 256 + ln15 * 16);
                b2 = *(const bf16x8*)(cur + 18432 + 512 + ln15 * 16);
            }
            #pragma unroll
            for (int Mt = 0; Mt < 4; ++Mt) {
                a0[Mt] = __builtin_amdgcn_mfma_f32_16x16x32_bf16(b0, af[Mt][kc], a0[Mt], 0, 0, 0);
                a1[Mt] = __builtin_amdgcn_mfma_f32_16x16x32_bf16(b1, af[Mt][kc], a1[Mt], 0, 0, 0);
                a2[Mt] = __builtin_amdgcn_mfma_f32_16x16x32_bf16(b2, af[Mt][kc], a2[Mt], 0, 0, 0);
            }
        }
        const int dir = s / 7, cc = s - dir * 7;
        if (cc * 16 + q * 4 < NHW) {
            const f32x4 bR = *(const f32x4*)(cur + 19200 +   0 + q * 16);
            const f32x4 bZ = *(const f32x4*)(cur + 19200 +  64 + q * 16);
            const f32x4 bN = *(const f32x4*)(cur + 19200 + 128 + q * 16);
            const f32x4 hN = *(const f32x4*)(cur + 19200 + 192 + q * 16);
            const int ub = dir * NHW + cc * 16 + q * 4;
            #pragma unroll
            for (int Mt = 0; Mt < 4; ++Mt) {
                const int item = Mt * 16 + ln15;
                float h[4];
                #pragma unroll
                for (int rg = 0; rg < 4; ++rg) {
                    const float r  = frcp(1.f + fexp2(fmaf(a0[Mt][rg], -KL2E, bR[rg])));
                    const float zc = frcp(1.f + fexp2(fmaf(a1[Mt][rg],  KL2E, bZ[rg])));
                    const float t  = frcp(1.f + fexp2(fmaf(a2[Mt][rg], 2.f * KL2E,
                                              fmaf(r, hN[rg], bN[rg]))));
                    h[rg] = zc * (1.f - 2.f * t);
                }
                if (item < nvalid) {
                    uint2 o; o.x = cvtpk(h[0], h[1]); o.y = cvtpk(h[2], h[3]);
                    *(uint2*)(Hme + (size_t)item * HST + ub * 2) = o;
                }
            }
        }
        __syncthreads();
    }

    // ---- hf fragments from own H (same-wave ds ordering via lgkmcnt) ----
    bf16x8 hf[4][7];
    #pragma unroll
    for (int Mt = 0; Mt < 4; ++Mt) {
        const int item = Mt * 16 + ln15;
        #pragma unroll
        for (int kc = 0; kc < 7; ++kc) {
            bf16x8 v = (bf16x8)(short)0;
            if (item < nvalid && (kc < 6 || q == 0))
                v = *(const bf16x8*)(Hme + (size_t)item * HST + kc * 64 + q * 16);
            hf[Mt][kc] = v;
        }
    }

    // =================== attn loop: s = 14..18 ===================
    float sacc[4][4] = {{0.f}};
    #pragma unroll 1
    for (int s = 14; s < 19; ++s) {
        if (s + 1 < 19)
            stageBlob(bufs + (size_t)((s + 1) & 1) * SLOT, pk + (size_t)(s + 1) * BBn, tid);
        const char* cur = bufs + (size_t)(s & 1) * SLOT;

        f32x4 ac[4][3] = {};
        #pragma unroll
        for (int kc = 0; kc < 7; ++kc) {
            bf16x8 b0, b1, b2;
            if (kc < 6) {
                b0 = *(const bf16x8*)(cur + ((kc * 3 + 0) << 10) + lane * 16);
                b1 = *(const bf16x8*)(cur + ((kc * 3 + 1) << 10) + lane * 16);
                b2 = *(const bf16x8*)(cur + ((kc * 3 + 2) << 10) + lane * 16);
            } else {
                b0 = *(const bf16x8*)(cur + 18432 +   0 + ln15 * 16);
                b1 = *(const bf16x8*)(cur + 18432 + 256 + ln15 * 16);
                b2 = *(const bf16x8*)(cur + 18432 + 512 + ln15 * 16);
            }
            #pragma unroll
            for (int Mt = 0; Mt < 4; ++Mt) {
                ac[Mt][0] = __builtin_amdgcn_mfma_f32_16x16x32_bf16(hf[Mt][kc], b0, ac[Mt][0], 0, 0, 0);
                ac[Mt][1] = __builtin_amdgcn_mfma_f32_16x16x32_bf16(hf[Mt][kc], b1, ac[Mt][1], 0, 0, 0);
                ac[Mt][2] = __builtin_amdgcn_mfma_f32_16x16x32_bf16(hf[Mt][kc], b2, ac[Mt][2], 0, 0, 0);
            }
        }
        // tanh(u)·cx folded: sacc += cx2n / (1 + exp2(2K·acc + ab2))
        #pragma unroll
        for (int Nt = 0; Nt < 3; ++Nt) {
            const float ab2 = *(const float*)(cur + 19200 + (Nt * 16 + ln15) * 4);
            const float cxn = *(const float*)(cur + 19392 + (Nt * 16 + ln15) * 4);
            #pragma unroll
            for (int Mt = 0; Mt < 4; ++Mt)
                #pragma unroll
                for (int rg = 0; rg < 4; ++rg) {
                    const float u = frcp(1.f + fexp2(fmaf(ac[Mt][Nt][rg], 2.f * KL2E, ab2)));
                    sacc[Mt][rg] = fmaf(u, cxn, sacc[Mt][rg]);
                }
        }
        __syncthreads();
    }

    // ======== wave-private tail: d-reduce, softmax, pooling, write ========
    // sacc[Mt][rg] holds partial score for item Mt*16 + q*4 + rg over d-lanes.
    #pragma unroll
    for (int Mt = 0; Mt < 4; ++Mt)
        #pragma unroll
        for (int rg = 0; rg < 4; ++rg) {
            float v = sacc[Mt][rg];
            v += __shfl_xor(v, 1); v += __shfl_xor(v, 2);
            v += __shfl_xor(v, 4); v += __shfl_xor(v, 8);
            sacc[Mt][rg] = v;                    // replicated over ln15
        }

    // in-wave softmax over all 64 items (invalid rows -> -1e30)
    float alpha[4][4];
    {
        float m = -1e30f;
        #pragma unroll
        for (int Mt = 0; Mt < 4; ++Mt)
            #pragma unroll
            for (int rg = 0; rg < 4; ++rg) {
                const int item = Mt * 16 + q * 4 + rg;
                sacc[Mt][rg] = (item < nvalid) ? sacc[Mt][rg] : -1e30f;
                m = fmaxf(m, sacc[Mt][rg]);
            }
        m = fmaxf(m, __shfl_xor(m, 16)); m = fmaxf(m, __shfl_xor(m, 32));
        float ss = 0.f;
        #pragma unroll
        for (int Mt = 0; Mt < 4; ++Mt)
            #pragma unroll
            for (int rg = 0; rg < 4; ++rg) {
                const float e = fexp2((sacc[Mt][rg] - m) * KL2E);   // 0 for -1e30
                alpha[Mt][rg] = e; ss += e;
            }
        ss += __shfl_xor(ss, 16); ss += __shfl_xor(ss, 32);
        const float inv = frcp(ss);
        #pragma unroll
        for (int Mt = 0; Mt < 4; ++Mt)
            #pragma unroll
            for (int rg = 0; rg < 4; ++rg)
                alpha[Mt][rg] *= inv;
    }

    // redistribute alpha by item via wave-private LDS scratch (H is dead)
    float* al = (float*)Hme;   // 64 floats
    if (ln15 == 0) {
        #pragma unroll
        for (int Mt = 0; Mt < 4; ++Mt) {
            f32x4 v = {alpha[Mt][0], alpha[Mt][1], alpha[Mt][2], alpha[Mt][3]};
            *(f32x4*)(al + Mt * 16 + q * 4) = v;
        }
    }
    float aM[4];
    #pragma unroll
    for (int Mt = 0; Mt < 4; ++Mt) aM[Mt] = al[Mt * 16 + ln15];

    // pooling: out[k = kc*32 + q*8 + j] = sum_item alpha[item] * H[item][k]
    #pragma unroll
    for (int kc = 0; kc < 7; ++kc) {
        float p[8];
        #pragma unroll
        for (int j = 0; j < 8; ++j) {
            p[j] = aM[0] * bf2f(hf[0][kc][j]);
            p[j] = fmaf(aM[1], bf2f(hf[1][kc][j]), p[j]);
            p[j] = fmaf(aM[2], bf2f(hf[2][kc][j]), p[j]);
            p[j] = fmaf(aM[3], bf2f(hf[3][kc][j]), p[j]);
        }
        #pragma unroll
        for (int j = 0; j < 8; ++j) {
            p[j] += __shfl_xor(p[j], 1); p[j] += __shfl_xor(p[j], 2);
            p[j] += __shfl_xor(p[j], 4); p[j] += __shfl_xor(p[j], 8);
        }
        if (ln15 == 0 && (kc < 6 || q == 0)) {
            u32x4 o;
            o[0] = cvtpk(p[0], p[1]); o[1] = cvtpk(p[2], p[3]);
            o[2] = cvtpk(p[4], p[5]); o[3] = cvtpk(p[6], p[7]);
            *(u32x4*)(Out + g * 200 + kc * 32 + q * 8) = o;
        }
    }
}

// ============================ classifier + log_softmax =====================
__global__ void cls_kernel(const unsigned short* __restrict__ dvec,
                           const float* __restrict__ fcW, const float* __restrict__ fcb,
                           float* __restrict__ out)
{
    const int doc = blockIdx.x, lane = threadIdx.x;  // 64 threads
    const int c = lane & 15, part = lane >> 4;
    const int cs = (c < NC) ? c : 0;
    float acc = (part == 0 && c < NC) ? fcb[c] : 0.f;
    for (int i = 0; i < 50; ++i) {
        const int k = part * 50 + i;
        const float a = bf2f((short)dvec[(size_t)doc * 200 + k]);
        acc += a * ((c < NC) ? fcW[(size_t)cs * 200 + k] : 0.f);
    }
    acc += __shfl_xor(acc, 16); acc += __shfl_xor(acc, 32);
    const float lg = (c < NC) ? acc : -1e30f;
    float m = lg;
    m = fmaxf(m, __shfl_xor(m, 1)); m = fmaxf(m, __shfl_xor(m, 2));
    m = fmaxf(m, __shfl_xor(m, 4)); m = fmaxf(m, __shfl_xor(m, 8));
    const float e = (c < NC) ? __expf(lg - m) : 0.f;
    float ss = e;
    ss += __shfl_xor(ss, 1); ss += __shfl_xor(ss, 2);
    ss += __shfl_xor(ss, 4); ss += __shfl_xor(ss, 8);
    const float lse = m + __logf(ss);
    if (lane < NC) out[(size_t)doc * NC + lane] = lg - lse;
}

// ======================================================================
// Fallback fp32 path — used only if ws_size < WS_NEED.
// ======================================================================
template<int NWRD, int WT>
__device__ __forceinline__ void encode_block(
    float* __restrict__ e_sh, float* __restrict__ h_sh, float* __restrict__ sc_sh,
    const float* __restrict__ Wf, const float* __restrict__ bihf, const float* __restrict__ bhhf,
    const float* __restrict__ Wb, const float* __restrict__ bihb, const float* __restrict__ bhhb,
    const float* __restrict__ aW, const float* __restrict__ ab, const float* __restrict__ actx,
    int tid)
{
    constexpr int WG = NWRD / WT;
    for (int item = tid; item < FEAT * WG; item += 256) {
        const int unit = item % FEAT, wg = item / FEAT;
        const int dir = unit / NHW, j = unit - dir * NHW;
        const float* Wd  = dir ? Wb : Wf;
        const float* bih = dir ? bihb : bihf;
        const float* bhh = dir ? bhhb : bhhf;
        const float4* rowR = (const float4*)(Wd + (size_t)j * ED);
        const float4* rowZ = (const float4*)(Wd + (size_t)(NHW + j) * ED);
        const float4* rowN = (const float4*)(Wd + (size_t)(2 * NHW + j) * ED);
        float aR[WT], aZ[WT], aN[WT];
        #pragma unroll
        for (int t = 0; t < WT; ++t) { aR[t] = 0.f; aZ[t] = 0.f; aN[t] = 0.f; }
        const int w0 = wg * WT;
        #pragma unroll 1
        for (int k4 = 0; k4 < ED / 4; ++k4) {
            const float4 wr = rowR[k4], wz = rowZ[k4], wn = rowN[k4];
            #pragma unroll
            for (int t = 0; t < WT; ++t) {
                const float4 e = *(const float4*)(e_sh + (w0 + t) * ED + k4 * 4);
                aR[t] += wr.x*e.x + wr.y*e.y + wr.z*e.z + wr.w*e.w;
                aZ[t] += wz.x*e.x + wz.y*e.y + wz.z*e.z + wz.w*e.w;
                aN[t] += wn.x*e.x + wn.y*e.y + wn.z*e.z + wn.w*e.w;
            }
        }
        const float bR = bih[j] + bhh[j], bZ = bih[NHW+j] + bhh[NHW+j];
        const float bN = bih[2*NHW+j], hN = bhh[2*NHW+j];
        #pragma unroll
        for (int t = 0; t < WT; ++t) {
            const float r = fsig(aR[t] + bR), z = fsig(aZ[t] + bZ);
            const float n = ftanh(aN[t] + bN + r * hN);
            h_sh[(w0 + t) * FEAT + unit] = (1.f - z) * n;
        }
    }
    __syncthreads();
    for (int item = tid; item < FEAT * WG; item += 256) {
        const int d = item % FEAT, wg = item / FEAT;
        const float4* row = (const float4*)(aW + (size_t)d * FEAT);
        float acc[WT];
        #pragma unroll
        for (int t = 0; t < WT; ++t) acc[t] = 0.f;
        const int w0 = wg * WT;
        #pragma unroll 1
        for (int k4 = 0; k4 < FEAT / 4; ++k4) {
            const float4 wv = row[k4];
            #pragma unroll
            for (int t = 0; t < WT; ++t) {
                const float4 h = *(const float4*)(h_sh + (w0 + t) * FEAT + k4 * 4);
                acc[t] += wv.x*h.x + wv.y*h.y + wv.z*h.z + wv.w*h.w;
            }
        }
        const float bb = ab[d], cc = actx[d];
        #pragma unroll
        for (int t = 0; t < WT; ++t)
            e_sh[d * NWRD + (w0 + t)] = ftanh(acc[t] + bb) * cc;
    }
    __syncthreads();
    if (tid < NWRD) {
        float s = 0.f;
        for (int d = 0; d < FEAT; ++d) s += e_sh[d * NWRD + tid];
        sc_sh[tid] = s;
    }
    __syncthreads();
    if (tid == 0) {
        float m = -1e30f;
        for (int w = 0; w < NWRD; ++w) m = fmaxf(m, sc_sh[w]);
        float s = 0.f;
        for (int w = 0; w < NWRD; ++w) { const float ev = __expf(sc_sh[w] - m); sc_sh[w] = ev; s += ev; }
        const float inv = 1.f / s;
        for (int w = 0; w < NWRD; ++w) sc_sh[w] *= inv;
    }
    __syncthreads();
}

__global__ __launch_bounds__(256) void word_kernel_f32(
    const int* __restrict__ x, const float* __restrict__ emb,
    const float* __restrict__ Wf, const float* __restrict__ bihf, const float* __restrict__ bhhf,
    const float* __restrict__ Wb, const float* __restrict__ bihb, const float* __restrict__ bhhb,
    const float* __restrict__ waW, const float* __restrict__ wab, const float* __restrict__ wactx,
    float* __restrict__ svec)
{
    __shared__ __align__(16) float e_sh[NW * ED];
    __shared__ __align__(16) float h_sh[NW * FEAT];
    __shared__ float sc_sh[NW];
    const int sent = blockIdx.x, tid = threadIdx.x;
    const int* xr = x + (size_t)sent * NW;
    for (int i = tid * 4; i < NW * ED; i += 256 * 4) {
        const int w = i / ED, k = i - w * ED;
        *(float4*)(e_sh + i) = *(const float4*)(emb + (size_t)xr[w] * ED + k);
    }
    __syncthreads();
    encode_block<NW, 25>(e_sh, h_sh, sc_sh, Wf, bihf, bhhf, Wb, bihb, bhhb, waW, wab, wactx, tid);
    if (tid < FEAT) {
        float a = 0.f;
        #pragma unroll 1
        for (int w = 0; w < NW; ++w) a += sc_sh[w] * h_sh[w * FEAT + tid];
        svec[(size_t)sent * FEAT + tid] = a;
    }
}

__global__ __launch_bounds__(256) void sent_kernel_f32(
    const float* __restrict__ svec,
    const float* __restrict__ Wf, const float* __restrict__ bihf, const float* __restrict__ bhhf,
    const float* __restrict__ Wb, const float* __restrict__ bihb, const float* __restrict__ bhhb,
    const float* __restrict__ saW, const float* __restrict__ sab, const float* __restrict__ sactx,
    const float* __restrict__ fcW, const float* __restrict__ fcb,
    float* __restrict__ out)
{
    __shared__ __align__(16) float e_sh[NS * ED];
    __shared__ __align__(16) float h_sh[NS * FEAT];
    __shared__ float sc_sh[NS];
    __shared__ float dvec_sh[FEAT];
    __shared__ float logit_sh[NC];
    __shared__ float lse_sh;
    const int b = blockIdx.x, tid = threadIdx.x;
    const float* src = svec + (size_t)b * NS * FEAT;
    for (int i = tid * 4; i < NS * FEAT; i += 256 * 4)
        *(float4*)(e_sh + i) = *(const float4*)(src + i);
    __syncthreads();
    encode_block<NS, 20>(e_sh, h_sh, sc_sh, Wf, bihf, bhhf, Wb, bihb, bhhb, saW, sab, sactx, tid);
    if (tid < FEAT) {
        float a = 0.f;
        #pragma unroll 1
        for (int s = 0; s < NS; ++s) a += sc_sh[s] * h_sh[s * FEAT + tid];
        dvec_sh[tid] = a;
    }
    __syncthreads();
    if (tid < NC) {
        float a = fcb[tid];
        const float* row = fcW + (size_t)tid * FEAT;
        for (int k = 0; k < FEAT; ++k) a += row[k] * dvec_sh[k];
        logit_sh[tid] = a;
    }
    __syncthreads();
    if (tid == 0) {
        float m = -1e30f;
        for (int c = 0; c < NC; ++c) m = fmaxf(m, logit_sh[c]);
        float s = 0.f;
        for (int c = 0; c < NC; ++c) s += __expf(logit_sh[c] - m);
        lse_sh = m + logf(s);
    }
    __syncthreads();
    if (tid < NC) out[(size_t)b * NC + tid] = logit_sh[tid] - lse_sh;
}

// ============================ launch =======================================
extern "C" void kernel_launch(void* const* d_in, const int* in_sizes, int n_in,
                              void* d_out, int out_size, void* d_ws, size_t ws_size,
                              hipStream_t stream)
{
    const int*   x     = (const int*)d_in[0];
    const float* emb   = (const float*)d_in[1];
    const float* wWf   = (const float*)d_in[2];
    const float* wbif  = (const float*)d_in[3];
    const float* wbhf  = (const float*)d_in[4];
    const float* wWb   = (const float*)d_in[5];
    const float* wbib  = (const float*)d_in[6];
    const float* wbhb  = (const float*)d_in[7];
    const float* waW   = (const float*)d_in[8];
    const float* wab   = (const float*)d_in[9];
    const float* wactx = (const float*)d_in[10];
    const float* sWf   = (const float*)d_in[11];
    const float* sbif  = (const float*)d_in[12];
    const float* sbhf  = (const float*)d_in[13];
    const float* sWb   = (const float*)d_in[14];
    const float* sbib  = (const float*)d_in[15];
    const float* sbhb  = (const float*)d_in[16];
    const float* saW   = (const float*)d_in[17];
    const float* sab   = (const float*)d_in[18];
    const float* sactx = (const float*)d_in[19];
    const float* fcW   = (const float*)d_in[20];
    const float* fcb   = (const float*)d_in[21];
    float* out = (float*)d_out;

    if (ws_size < WS_NEED) {
        float* svec = (float*)d_ws;
        word_kernel_f32<<<NB * NS, 256, 0, stream>>>(
            x, emb, wWf, wbif, wbhf, wWb, wbib, wbhb, waW, wab, wactx, svec);
        sent_kernel_f32<<<NB, 256, 0, stream>>>(
            svec, sWf, sbif, sbhf, sWb, sbib, sbhb, saW, sab, sactx, fcW, fcb, out);
        return;
    }

    char* ws = (char*)d_ws;
    unsigned short* svec = (unsigned short*)(ws + OFF_SV);
    unsigned short* dvec = (unsigned short*)(ws + OFF_DV);

    pack_kernel<<<38, 256, 0, stream>>>(
        wWf, wbif, wbhf, wWb, wbib, wbhb, waW, wab, wactx,
        sWf, sbif, sbhf, sWb, sbib, sbhb, saW, sab, sactx, ws);

    // word stage: 5120 sentences / 2 per block (128 thr, 1 wave per sentence)
    han_kernel<true><<<NB * NS / 2, 128, 0, stream>>>(
        x, emb, ws, NW, svec);

    // sentence stage: 128 docs / 2 per block
    han_kernel<false><<<NB / 2, 128, 0, stream>>>(
        nullptr, svec, ws + 19ull * BBn, NS, dvec);

    cls_kernel<<<NB, 64, 0, stream>>>(dvec, fcW, fcb, out);
}

// Round 6
// 337.436 us; speedup vs baseline: 2.3794x; 1.2249x over previous
//
#include <hip/hip_runtime.h>
#include <math.h>

// ============================ problem constants ============================
#define NB    128
#define NS    40
#define NW    50
#define ED    200   // = 2*HW = 2*HS
#define NHW   100
#define FEAT  200
#define NC    10
#define VOCABM1 99999
#define KL2E  1.4426950408889634f

// ============================ ws memory map (bytes) ========================
// v7 blobs, fragment order. GRU blobs (s=0..13) are ROW-PERMUTED so that
// stage s produces exactly units u(s,q,rg) = (s>>1)*32 + q*8 + (s&1)*4 + rg
// of the concatenated [fwd(0..99), bwd(100..199), pad(200..223)] h-vector.
// Then the MFMA C-output IS the attn A-fragment: hf[kc] = stages 2kc,2kc+1.
// Layout per blob:
//   kc=0..5 K-chunks: 18 fragments x 1024 B at f*1024, f = kk*3 + gate;
//     lane l: row i=l&15 (unit u(s,i)), k-elems kk*32+(l>>4)*8..+8 (bf16,
//     zero for pad rows).
//   kk=6 compact: 3 x 256 B at 18432 + gate*256 + i*16, k=192..200.
//   consts at 19200: GRU bias[4 sect][16] f32 (bR',bZ',bN2,hN2), unit-
//     permuted to match; attn: ab2[48] f32 at 19200, cxn[48] at 19392.
// Blob stride 19,712 B; 38 blobs (word 0..18, sent 19..37) = 749,056 B.
#define BBn      19712ull
#define OFF_SV   846336ull             // svec [5120][200] bf16 = 2,048,000
#define OFF_DV   2894336ull            // dvec [128][200] bf16 = 51,200
#define WS_NEED  4194304ull            // covers fp32 fallback's svec too

// LDS: 2 staging slots ONLY (no H!) = 39,424 B -> 3 blocks/CU (VGPR-capped).
#define SLOT   19712

// ============================ helpers ======================================
typedef short bf16x8 __attribute__((ext_vector_type(8)));
typedef float f32x4  __attribute__((ext_vector_type(4)));
typedef unsigned u32x4 __attribute__((ext_vector_type(4)));

__device__ __forceinline__ unsigned short f2bf(float f) {
    unsigned int u = __float_as_uint(f);
    u += 0x7fffu + ((u >> 16) & 1u);          // RNE
    return (unsigned short)(u >> 16);
}
__device__ __forceinline__ float bf2f(short s) {
    return __uint_as_float(((unsigned int)(unsigned short)s) << 16);
}
__device__ __forceinline__ unsigned pk2(float a, float b) {
    return (unsigned)f2bf(a) | ((unsigned)f2bf(b) << 16);
}
__device__ __forceinline__ float frcp(float x) { return __builtin_amdgcn_rcpf(x); }
#if __has_builtin(__builtin_amdgcn_exp2f)
__device__ __forceinline__ float fexp2(float x){ return __builtin_amdgcn_exp2f(x); }
#else
__device__ __forceinline__ float fexp2(float x){ return exp2f(x); }
#endif
__device__ __forceinline__ float fsig(float x) { return frcp(1.f + __expf(-x)); }
__device__ __forceinline__ float ftanh(float x){ return 1.f - 2.f*frcp(1.f + __expf(2.f*x)); }

// HW packed f32->bf16 (RNE), 1 inst per 2 values
__device__ __forceinline__ unsigned cvtpk(float lo, float hi) {
    unsigned r;
    asm("v_cvt_pk_bf16_f32 %0, %1, %2" : "=v"(r) : "v"(lo), "v"(hi));
    return r;
}
__device__ __forceinline__ bf16x8 pack8(float4 a, float4 b) {
    u32x4 t;
    t[0] = cvtpk(a.x, a.y); t[1] = cvtpk(a.z, a.w);
    t[2] = cvtpk(b.x, b.y); t[3] = cvtpk(b.z, b.w);
    return __builtin_bit_cast(bf16x8, t);
}

// async global->LDS, 16B per lane; LDS dst = wave-uniform base + lane*16.
__device__ __forceinline__ void gld16(const void* g, void* l) {
    __builtin_amdgcn_global_load_lds(
        (const __attribute__((address_space(1))) void*)g,
        (__attribute__((address_space(3))) void*)l, 16, 0, 0);
}

// stage one 19,712-B blob with 256 threads: 1232 16B units (4/thr + 208)
__device__ __forceinline__ void stageBlob(char* __restrict__ dst,
                                          const char* __restrict__ src, int tid)
{
    #pragma unroll
    for (int u = 0; u < 4; ++u)
        gld16(src + (size_t)(u * 256 + tid) * 16, dst + (size_t)(u * 256 + tid) * 16);
    if (tid < 208)
        gld16(src + (size_t)(1024 + tid) * 16, dst + (size_t)(1024 + tid) * 16);
}

// ============================ P1: weight packing ===========================
// One block per blob (38). GRU rows are unit-permuted: fragment row i of
// stage s holds W/bias for unit u = (s>>1)*32 + (i>>2)*8 + (s&1)*4 + (i&3);
// u<100 -> fwd row u; 100<=u<200 -> bwd row u-100; u>=200 -> zeros.
__global__ void pack_kernel(
    const float* __restrict__ wWf, const float* __restrict__ wbif, const float* __restrict__ wbhf,
    const float* __restrict__ wWb, const float* __restrict__ wbib, const float* __restrict__ wbhb,
    const float* __restrict__ waW, const float* __restrict__ wab, const float* __restrict__ wactx,
    const float* __restrict__ sWf, const float* __restrict__ sbif, const float* __restrict__ sbhf,
    const float* __restrict__ sWb, const float* __restrict__ sbib, const float* __restrict__ sbhb,
    const float* __restrict__ saW, const float* __restrict__ sab, const float* __restrict__ sactx,
    char* __restrict__ ws)
{
    const int b = blockIdx.x, tid = threadIdx.x;
    const bool word = b < 19;
    const int lb = word ? b : b - 19;
    char* blob = ws + (size_t)b * BBn;

    if (lb < 14) {
        const int s = lb;
        const float* Wf_ = word ? wWf : sWf;
        const float* Wb_ = word ? wWb : sWb;
        const float* bif = word ? wbif : sbif;
        const float* bhf = word ? wbhf : sbhf;
        const float* bib = word ? wbib : sbib;
        const float* bhb = word ? wbhb : sbhb;
        const int ub = (s >> 1) * 32 + (s & 1) * 4;

        for (int e = tid; e < 18 * 64; e += 256) {           // kk 0..5 fragments
            const int f = e >> 6, l = e & 63;
            const int gate = f % 3, kk = f / 3;
            const int i = l & 15;
            const int k0 = kk * 32 + (l >> 4) * 8;           // <= 184
            const int u = ub + ((i >> 2) << 3) + (i & 3);
            u32x4 out = {0u, 0u, 0u, 0u};
            if (u < 200) {
                const float* W = (u < 100) ? Wf_ : Wb_;
                const int j = (u < 100) ? u : u - 100;
                const float* src = W + (size_t)(gate * NHW + j) * ED + k0;
                out[0] = pk2(src[0], src[1]); out[1] = pk2(src[2], src[3]);
                out[2] = pk2(src[4], src[5]); out[3] = pk2(src[6], src[7]);
            }
            *(u32x4*)(blob + ((size_t)f << 10) + (size_t)l * 16) = out;
        }
        if (tid < 48) {                                      // kk 6 compact
            const int gate = tid >> 4, i = tid & 15;
            const int u = ub + ((i >> 2) << 3) + (i & 3);
            u32x4 out = {0u, 0u, 0u, 0u};
            if (u < 200) {
                const float* W = (u < 100) ? Wf_ : Wb_;
                const int j = (u < 100) ? u : u - 100;
                const float* src = W + (size_t)(gate * NHW + j) * ED + 192;
                out[0] = pk2(src[0], src[1]); out[1] = pk2(src[2], src[3]);
                out[2] = pk2(src[4], src[5]); out[3] = pk2(src[6], src[7]);
            }
            *(u32x4*)(blob + 18432 + gate * 256 + i * 16) = out;
        }
        if (tid < 64) {                                      // permuted biases
            const int sect = tid >> 4, i = tid & 15;
            const int u = ub + ((i >> 2) << 3) + (i & 3);
            float v = 0.f;
            if (u < 200) {
                const float* bih = (u < 100) ? bif : bib;
                const float* bhh = (u < 100) ? bhf : bhb;
                const int j = (u < 100) ? u : u - 100;
                if (sect == 0)      v = -KL2E * (bih[j] + bhh[j]);
                else if (sect == 1) v =  KL2E * (bih[NHW + j] + bhh[NHW + j]);
                else if (sect == 2) v = 2.f * KL2E * bih[2 * NHW + j];
                else                v = 2.f * KL2E * bhh[2 * NHW + j];
            }
            *(float*)(blob + 19200 + sect * 64 + i * 4) = v;
        }
    } else {
        const int cb = lb - 14;
        const float* W  = word ? waW : saW;
        const float* ab = word ? wab : sab;
        const float* cx = word ? wactx : sactx;
        for (int e = tid; e < 18 * 64; e += 256) {
            const int f = e >> 6, l = e & 63;
            const int g = f % 3, kk = f / 3;
            const int d = cb * 48 + g * 16 + (l & 15);
            const int k0 = kk * 32 + (l >> 4) * 8;
            u32x4 out = {0u, 0u, 0u, 0u};
            if (d < FEAT) {
                const float* src = W + (size_t)d * FEAT + k0;
                out[0] = pk2(src[0], src[1]); out[1] = pk2(src[2], src[3]);
                out[2] = pk2(src[4], src[5]); out[3] = pk2(src[6], src[7]);
            }
            *(u32x4*)(blob + ((size_t)f << 10) + (size_t)l * 16) = out;
        }
        if (tid < 48) {
            const int g = tid >> 4, i = tid & 15;
            const int d = cb * 48 + g * 16 + i;
            u32x4 out = {0u, 0u, 0u, 0u};
            if (d < FEAT) {
                const float* src = W + (size_t)d * FEAT + 192;
                out[0] = pk2(src[0], src[1]); out[1] = pk2(src[2], src[3]);
                out[2] = pk2(src[4], src[5]); out[3] = pk2(src[6], src[7]);
            }
            *(u32x4*)(blob + 18432 + g * 256 + i * 16) = out;
        }
        if (tid < 48) {
            const int d = cb * 48 + tid;
            float ab2 = 0.f, cxn = 0.f;
            if (d < FEAT) { ab2 = 2.f * KL2E * ab[d]; cxn = -2.f * cx[d]; }
            *(float*)(blob + 19200 + tid * 4) = ab2;
            *(float*)(blob + 19392 + tid * 4) = cxn;
        }
    }
}

// ============================ fused HAN stage kernel =======================
// v7: block = 2 groups x 2 waves (256 thr), Mt=2. NO H in LDS: GRU blobs are
// unit-permuted so stage s's MFMA C-output IS hf[s>>1] elements (s&1)*4..+4
// -> h packs straight into registers (hfw[2][7] u32x4). Pad units (>=200):
// zero weights+biases give h = 0.5*(1-2*0.5) = 0 exactly -> zero-padded attn
// rows, bit-identical to the old masked path. LDS = 2 staging slots only
// (39.4 KB) -> 3 blocks/CU (VGPR-capped), 12 waves/CU = 3/SIMD for latency
// hiding. Loops fully unrolled (static hfw indexing, rule #20). Tail scratch
// aliases slot 0 after the loop's final barrier.
template<bool WORD>
__global__ __launch_bounds__(256, 3) void han_kernel(
    const int* __restrict__ xtok,
    const void* __restrict__ Ain,
    const char* __restrict__ pk,     // 19 blobs, stride BBn (GRU 0..13, attn 14..18)
    const int nvalid,                // 50 / 40
    unsigned short* __restrict__ Out)
{
    __shared__ __align__(16) char smem[2 * SLOT];   // 39,424
    char* bufs = smem;

    const int tid  = threadIdx.x;
    const int lane = tid & 63, wv = tid >> 6;
    const int grp  = wv >> 1, half = wv & 1;
    const int ln15 = lane & 15, q = lane >> 4;
    const long g   = (long)blockIdx.x * 2 + grp;
    // tail scratch (slot 0 alias, used only after the stage loop)
    float* sc_sh = (float*)(bufs + grp * 4096);         // 64 f32
    float* al_sh = (float*)(bufs + grp * 4096 + 256);   // 64 f32
    float* part  = (float*)(bufs + grp * 4096 + 512);   // [2][224] f32

    // ---- prologue staging: slot 0 = blob 0 ----
    stageBlob(bufs, pk, tid);

    // ---- A fragments (overlap staging latency) ----
    bf16x8 af[2][7];
    if (WORD) {
        const float* emb = (const float*)Ain;
        #pragma unroll
        for (int Mt = 0; Mt < 2; ++Mt) {
            const int item = half * 32 + Mt * 16 + ln15;
            int tok = VOCABM1;                       // padding row: all zeros
            if (item < nvalid) tok = xtok[g * nvalid + item];
            const float4* rp = (const float4*)(emb + (long)tok * ED);
            #pragma unroll
            for (int kc = 0; kc < 6; ++kc)
                af[Mt][kc] = pack8(rp[kc * 8 + q * 2], rp[kc * 8 + q * 2 + 1]);
            af[Mt][6] = (q == 0) ? pack8(rp[48], rp[49]) : (bf16x8)(short)0;
        }
    } else {
        const char* sv = (const char*)Ain;
        #pragma unroll
        for (int Mt = 0; Mt < 2; ++Mt) {
            const int item = half * 32 + Mt * 16 + ln15;
            const int ic = item < nvalid ? item : nvalid - 1;
            const char* rp = sv + (g * nvalid + ic) * 400;
            #pragma unroll
            for (int kc = 0; kc < 7; ++kc) {
                bf16x8 v = (bf16x8)(short)0;
                if (item < nvalid && (kc < 6 || q == 0))
                    v = *(const bf16x8*)(rp + kc * 64 + q * 16);
                af[Mt][kc] = v;
            }
        }
    }

    __syncthreads();   // slot 0 resident

    // h fragments accumulate here: hfw[Mt][kc] = 4 u32 (8 bf16 units)
    u32x4 hfw[2][7];

    // =================== GRU stages s = 0..13 (unrolled) ===================
    #pragma unroll
    for (int s = 0; s < 14; ++s) {
        stageBlob(bufs + (size_t)((s + 1) & 1) * SLOT, pk + (size_t)(s + 1) * BBn, tid);
        const char* cur = bufs + (size_t)(s & 1) * SLOT;

        f32x4 a0[2] = {}, a1[2] = {}, a2[2] = {};
        #pragma unroll
        for (int kk = 0; kk < 7; ++kk) {
            bf16x8 b0, b1, b2;
            if (kk < 6) {
                b0 = *(const bf16x8*)(cur + ((kk * 3 + 0) << 10) + lane * 16);
                b1 = *(const bf16x8*)(cur + ((kk * 3 + 1) << 10) + lane * 16);
                b2 = *(const bf16x8*)(cur + ((kk * 3 + 2) << 10) + lane * 16);
            } else {     // compact; q>=1 lanes broadcast q==0 data (af=0 there)
                b0 = *(const bf16x8*)(cur + 18432 +   0 + ln15 * 16);
                b1 = *(const bf16x8*)(cur + 18432 + 256 + ln15 * 16);
                b2 = *(const bf16x8*)(cur + 18432 + 512 + ln15 * 16);
            }
            #pragma unroll
            for (int Mt = 0; Mt < 2; ++Mt) {
                a0[Mt] = __builtin_amdgcn_mfma_f32_16x16x32_bf16(b0, af[Mt][kk], a0[Mt], 0, 0, 0);
                a1[Mt] = __builtin_amdgcn_mfma_f32_16x16x32_bf16(b1, af[Mt][kk], a1[Mt], 0, 0, 0);
                a2[Mt] = __builtin_amdgcn_mfma_f32_16x16x32_bf16(b2, af[Mt][kk], a2[Mt], 0, 0, 0);
            }
        }
        const f32x4 bR = *(const f32x4*)(cur + 19200 +   0 + q * 16);
        const f32x4 bZ = *(const f32x4*)(cur + 19200 +  64 + q * 16);
        const f32x4 bN = *(const f32x4*)(cur + 19200 + 128 + q * 16);
        const f32x4 hN = *(const f32x4*)(cur + 19200 + 192 + q * 16);
        #pragma unroll
        for (int Mt = 0; Mt < 2; ++Mt) {
            float h[4];
            #pragma unroll
            for (int rg = 0; rg < 4; ++rg) {
                const float r  = frcp(1.f + fexp2(fmaf(a0[Mt][rg], -KL2E, bR[rg])));
                const float zc = frcp(1.f + fexp2(fmaf(a1[Mt][rg],  KL2E, bZ[rg])));
                const float t  = frcp(1.f + fexp2(fmaf(a2[Mt][rg], 2.f * KL2E,
                                          fmaf(r, hN[rg], bN[rg]))));
                h[rg] = zc * (1.f - 2.f * t);
            }
            hfw[Mt][s >> 1][(s & 1) * 2 + 0] = cvtpk(h[0], h[1]);
            hfw[Mt][s >> 1][(s & 1) * 2 + 1] = cvtpk(h[2], h[3]);
        }
        __syncthreads();
    }

    // =================== attn stages s = 14..18 (unrolled) =================
    float sacc[2][4] = {{0.f}};
    #pragma unroll
    for (int s = 14; s < 19; ++s) {
        if (s + 1 < 19)
            stageBlob(bufs + (size_t)((s + 1) & 1) * SLOT, pk + (size_t)(s + 1) * BBn, tid);
        const char* cur = bufs + (size_t)(s & 1) * SLOT;

        f32x4 ac[2][3] = {};
        #pragma unroll
        for (int kk = 0; kk < 7; ++kk) {
            bf16x8 b0, b1, b2;
            if (kk < 6) {
                b0 = *(const bf16x8*)(cur + ((kk * 3 + 0) << 10) + lane * 16);
                b1 = *(const bf16x8*)(cur + ((kk * 3 + 1) << 10) + lane * 16);
                b2 = *(const bf16x8*)(cur + ((kk * 3 + 2) << 10) + lane * 16);
            } else {
                b0 = *(const bf16x8*)(cur + 18432 +   0 + ln15 * 16);
                b1 = *(const bf16x8*)(cur + 18432 + 256 + ln15 * 16);
                b2 = *(const bf16x8*)(cur + 18432 + 512 + ln15 * 16);
            }
            #pragma unroll
            for (int Mt = 0; Mt < 2; ++Mt) {
                const bf16x8 hfv = __builtin_bit_cast(bf16x8, hfw[Mt][kk]);
                ac[Mt][0] = __builtin_amdgcn_mfma_f32_16x16x32_bf16(hfv, b0, ac[Mt][0], 0, 0, 0);
                ac[Mt][1] = __builtin_amdgcn_mfma_f32_16x16x32_bf16(hfv, b1, ac[Mt][1], 0, 0, 0);
                ac[Mt][2] = __builtin_amdgcn_mfma_f32_16x16x32_bf16(hfv, b2, ac[Mt][2], 0, 0, 0);
            }
        }
        // tanh(u)·cx folded: sacc += cx2n / (1 + exp2(2K·acc + ab2))
        #pragma unroll
        for (int Nt = 0; Nt < 3; ++Nt) {
            const float ab2 = *(const float*)(cur + 19200 + (Nt * 16 + ln15) * 4);
            const float cxn = *(const float*)(cur + 19392 + (Nt * 16 + ln15) * 4);
            #pragma unroll
            for (int Mt = 0; Mt < 2; ++Mt)
                #pragma unroll
                for (int rg = 0; rg < 4; ++rg) {
                    const float u = frcp(1.f + fexp2(fmaf(ac[Mt][Nt][rg], 2.f * KL2E, ab2)));
                    sacc[Mt][rg] = fmaf(u, cxn, sacc[Mt][rg]);
                }
        }
        __syncthreads();
    }

    // ======== tail: d-reduce, cross-wave softmax, pooling, write ==========
    // sacc[Mt][rg] = partial score of item half*32+Mt*16+q*4+rg over d (ln15)
    #pragma unroll
    for (int Mt = 0; Mt < 2; ++Mt)
        #pragma unroll
        for (int rg = 0; rg < 4; ++rg) {
            float v = sacc[Mt][rg];
            v += __shfl_xor(v, 1); v += __shfl_xor(v, 2);
            v += __shfl_xor(v, 4); v += __shfl_xor(v, 8);
            sacc[Mt][rg] = v;
        }
    // slots are dead after the loop's final barrier -> scratch alias safe
    if (ln15 == 0) {
        #pragma unroll
        for (int Mt = 0; Mt < 2; ++Mt)
            #pragma unroll
            for (int rg = 0; rg < 4; ++rg)
                sc_sh[half * 32 + Mt * 16 + q * 4 + rg] = sacc[Mt][rg];
    }
    __syncthreads();

    // ---- per-group softmax over 64 padded rows (exp2-scaled) ----
    {
        const float sv0 = (lane < nvalid) ? sc_sh[lane] : -1e30f;
        float m = sv0;
        m = fmaxf(m, __shfl_xor(m, 1));  m = fmaxf(m, __shfl_xor(m, 2));
        m = fmaxf(m, __shfl_xor(m, 4));  m = fmaxf(m, __shfl_xor(m, 8));
        m = fmaxf(m, __shfl_xor(m, 16)); m = fmaxf(m, __shfl_xor(m, 32));
        const float e = (lane < nvalid) ? fexp2((sv0 - m) * KL2E) : 0.f;
        float ss = e;
        ss += __shfl_xor(ss, 1);  ss += __shfl_xor(ss, 2);
        ss += __shfl_xor(ss, 4);  ss += __shfl_xor(ss, 8);
        ss += __shfl_xor(ss, 16); ss += __shfl_xor(ss, 32);
        if (half == 0) al_sh[lane] = e * frcp(ss);
    }
    __syncthreads();

    // ---- pooling straight from hfw fragments ----
    {
        const float aM0 = al_sh[half * 32 + ln15];
        const float aM1 = al_sh[half * 32 + 16 + ln15];
        #pragma unroll
        for (int kc = 0; kc < 7; ++kc) {
            const bf16x8 h0 = __builtin_bit_cast(bf16x8, hfw[0][kc]);
            const bf16x8 h1 = __builtin_bit_cast(bf16x8, hfw[1][kc]);
            float p[8];
            #pragma unroll
            for (int j = 0; j < 8; ++j)
                p[j] = aM0 * bf2f(h0[j]) + aM1 * bf2f(h1[j]);
            #pragma unroll
            for (int j = 0; j < 8; ++j) {
                p[j] += __shfl_xor(p[j], 1); p[j] += __shfl_xor(p[j], 2);
                p[j] += __shfl_xor(p[j], 4); p[j] += __shfl_xor(p[j], 8);
            }
            if (ln15 == 0) {
                float* dst = part + (size_t)half * 224 + kc * 32 + q * 8;
                f32x4 v0 = {p[0], p[1], p[2], p[3]};
                f32x4 v1 = {p[4], p[5], p[6], p[7]};
                *(f32x4*)dst = v0; *(f32x4*)(dst + 4) = v1;
            }
        }
    }
    __syncthreads();

    // ---- combine halves, write pooled bf16 rows ----
    if (tid < 100) {
        const int sl = tid / 50, i = tid - sl * 50;     // i*4 = k0 < 200
        const float* pa = (const float*)(bufs + (size_t)sl * 4096 + 512);
        const float* pb = pa + 224;
        uint2 o;
        o.x = cvtpk(pa[i * 4 + 0] + pb[i * 4 + 0], pa[i * 4 + 1] + pb[i * 4 + 1]);
        o.y = cvtpk(pa[i * 4 + 2] + pb[i * 4 + 2], pa[i * 4 + 3] + pb[i * 4 + 3]);
        *(uint2*)(Out + ((long)blockIdx.x * 2 + sl) * 200 + i * 4) = o;
    }
}

// ============================ classifier + log_softmax =====================
__global__ void cls_kernel(const unsigned short* __restrict__ dvec,
                           const float* __restrict__ fcW, const float* __restrict__ fcb,
                           float* __restrict__ out)
{
    const int doc = blockIdx.x, lane = threadIdx.x;  // 64 threads
    const int c = lane & 15, part = lane >> 4;
    const int cs = (c < NC) ? c : 0;
    float acc = (part == 0 && c < NC) ? fcb[c] : 0.f;
    for (int i = 0; i < 50; ++i) {
        const int k = part * 50 + i;
        const float a = bf2f((short)dvec[(size_t)doc * 200 + k]);
        acc += a * ((c < NC) ? fcW[(size_t)cs * 200 + k] : 0.f);
    }
    acc += __shfl_xor(acc, 16); acc += __shfl_xor(acc, 32);
    const float lg = (c < NC) ? acc : -1e30f;
    float m = lg;
    m = fmaxf(m, __shfl_xor(m, 1)); m = fmaxf(m, __shfl_xor(m, 2));
    m = fmaxf(m, __shfl_xor(m, 4)); m = fmaxf(m, __shfl_xor(m, 8));
    const float e = (c < NC) ? __expf(lg - m) : 0.f;
    float ss = e;
    ss += __shfl_xor(ss, 1); ss += __shfl_xor(ss, 2);
    ss += __shfl_xor(ss, 4); ss += __shfl_xor(ss, 8);
    const float lse = m + __logf(ss);
    if (lane < NC) out[(size_t)doc * NC + lane] = lg - lse;
}

// ======================================================================
// Fallback fp32 path — used only if ws_size < WS_NEED.
// ======================================================================
template<int NWRD, int WT>
__device__ __forceinline__ void encode_block(
    float* __restrict__ e_sh, float* __restrict__ h_sh, float* __restrict__ sc_sh,
    const float* __restrict__ Wf, const float* __restrict__ bihf, const float* __restrict__ bhhf,
    const float* __restrict__ Wb, const float* __restrict__ bihb, const float* __restrict__ bhhb,
    const float* __restrict__ aW, const float* __restrict__ ab, const float* __restrict__ actx,
    int tid)
{
    constexpr int WG = NWRD / WT;
    for (int item = tid; item < FEAT * WG; item += 256) {
        const int unit = item % FEAT, wg = item / FEAT;
        const int dir = unit / NHW, j = unit - dir * NHW;
        const float* Wd  = dir ? Wb : Wf;
        const float* bih = dir ? bihb : bihf;
        const float* bhh = dir ? bhhb : bhhf;
        const float4* rowR = (const float4*)(Wd + (size_t)j * ED);
        const float4* rowZ = (const float4*)(Wd + (size_t)(NHW + j) * ED);
        const float4* rowN = (const float4*)(Wd + (size_t)(2 * NHW + j) * ED);
        float aR[WT], aZ[WT], aN[WT];
        #pragma unroll
        for (int t = 0; t < WT; ++t) { aR[t] = 0.f; aZ[t] = 0.f; aN[t] = 0.f; }
        const int w0 = wg * WT;
        #pragma unroll 1
        for (int k4 = 0; k4 < ED / 4; ++k4) {
            const float4 wr = rowR[k4], wz = rowZ[k4], wn = rowN[k4];
            #pragma unroll
            for (int t = 0; t < WT; ++t) {
                const float4 e = *(const float4*)(e_sh + (w0 + t) * ED + k4 * 4);
                aR[t] += wr.x*e.x + wr.y*e.y + wr.z*e.z + wr.w*e.w;
                aZ[t] += wz.x*e.x + wz.y*e.y + wz.z*e.z + wz.w*e.w;
                aN[t] += wn.x*e.x + wn.y*e.y + wn.z*e.z + wn.w*e.w;
            }
        }
        const float bR = bih[j] + bhh[j], bZ = bih[NHW+j] + bhh[NHW+j];
        const float bN = bih[2*NHW+j], hN = bhh[2*NHW+j];
        #pragma unroll
        for (int t = 0; t < WT; ++t) {
            const float r = fsig(aR[t] + bR), z = fsig(aZ[t] + bZ);
            const float n = ftanh(aN[t] + bN + r * hN);
            h_sh[(w0 + t) * FEAT + unit] = (1.f - z) * n;
        }
    }
    __syncthreads();
    for (int item = tid; item < FEAT * WG; item += 256) {
        const int d = item % FEAT, wg = item / FEAT;
        const float4* row = (const float4*)(aW + (size_t)d * FEAT);
        float acc[WT];
        #pragma unroll
        for (int t = 0; t < WT; ++t) acc[t] = 0.f;
        const int w0 = wg * WT;
        #pragma unroll 1
        for (int k4 = 0; k4 < FEAT / 4; ++k4) {
            const float4 wv = row[k4];
            #pragma unroll
            for (int t = 0; t < WT; ++t) {
                const float4 h = *(const float4*)(h_sh + (w0 + t) * FEAT + k4 * 4);
                acc[t] += wv.x*h.x + wv.y*h.y + wv.z*h.z + wv.w*h.w;
            }
        }
        const float bb = ab[d], cc = actx[d];
        #pragma unroll
        for (int t = 0; t < WT; ++t)
            e_sh[d * NWRD + (w0 + t)] = ftanh(acc[t] + bb) * cc;
    }
    __syncthreads();
    if (tid < NWRD) {
        float s = 0.f;
        for (int d = 0; d < FEAT; ++d) s += e_sh[d * NWRD + tid];
        sc_sh[tid] = s;
    }
    __syncthreads();
    if (tid == 0) {
        float m = -1e30f;
        for (int w = 0; w < NWRD; ++w) m = fmaxf(m, sc_sh[w]);
        float s = 0.f;
        for (int w = 0; w < NWRD; ++w) { const float ev = __expf(sc_sh[w] - m); sc_sh[w] = ev; s += ev; }
        const float inv = 1.f / s;
        for (int w = 0; w < NWRD; ++w) sc_sh[w] *= inv;
    }
    __syncthreads();
}

__global__ __launch_bounds__(256) void word_kernel_f32(
    const int* __restrict__ x, const float* __restrict__ emb,
    const float* __restrict__ Wf, const float* __restrict__ bihf, const float* __restrict__ bhhf,
    const float* __restrict__ Wb, const float* __restrict__ bihb, const float* __restrict__ bhhb,
    const float* __restrict__ waW, const float* __restrict__ wab, const float* __restrict__ wactx,
    float* __restrict__ svec)
{
    __shared__ __align__(16) float e_sh[NW * ED];
    __shared__ __align__(16) float h_sh[NW * FEAT];
    __shared__ float sc_sh[NW];
    const int sent = blockIdx.x, tid = threadIdx.x;
    const int* xr = x + (size_t)sent * NW;
    for (int i = tid * 4; i < NW * ED; i += 256 * 4) {
        const int w = i / ED, k = i - w * ED;
        *(float4*)(e_sh + i) = *(const float4*)(emb + (size_t)xr[w] * ED + k);
    }
    __syncthreads();
    encode_block<NW, 25>(e_sh, h_sh, sc_sh, Wf, bihf, bhhf, Wb, bihb, bhhb, waW, wab, wactx, tid);
    if (tid < FEAT) {
        float a = 0.f;
        #pragma unroll 1
        for (int w = 0; w < NW; ++w) a += sc_sh[w] * h_sh[w * FEAT + tid];
        svec[(size_t)sent * FEAT + tid] = a;
    }
}

__global__ __launch_bounds__(256) void sent_kernel_f32(
    const float* __restrict__ svec,
    const float* __restrict__ Wf, const float* __restrict__ bihf, const float* __restrict__ bhhf,
    const float* __restrict__ Wb, const float* __restrict__ bihb, const float* __restrict__ bhhb,
    const float* __restrict__ saW, const float* __restrict__ sab, const float* __restrict__ sactx,
    const float* __restrict__ fcW, const float* __restrict__ fcb,
    float* __restrict__ out)
{
    __shared__ __align__(16) float e_sh[NS * ED];
    __shared__ __align__(16) float h_sh[NS * FEAT];
    __shared__ float sc_sh[NS];
    __shared__ float dvec_sh[FEAT];
    __shared__ float logit_sh[NC];
    __shared__ float lse_sh;
    const int b = blockIdx.x, tid = threadIdx.x;
    const float* src = svec + (size_t)b * NS * FEAT;
    for (int i = tid * 4; i < NS * FEAT; i += 256 * 4)
        *(float4*)(e_sh + i) = *(const float4*)(src + i);
    __syncthreads();
    encode_block<NS, 20>(e_sh, h_sh, sc_sh, Wf, bihf, bhhf, Wb, bihb, bhhb, saW, sab, sactx, tid);
    if (tid < FEAT) {
        float a = 0.f;
        #pragma unroll 1
        for (int s = 0; s < NS; ++s) a += sc_sh[s] * h_sh[s * FEAT + tid];
        dvec_sh[tid] = a;
    }
    __syncthreads();
    if (tid < NC) {
        float a = fcb[tid];
        const float* row = fcW + (size_t)tid * FEAT;
        for (int k = 0; k < FEAT; ++k) a += row[k] * dvec_sh[k];
        logit_sh[tid] = a;
    }
    __syncthreads();
    if (tid == 0) {
        float m = -1e30f;
        for (int c = 0; c < NC; ++c) m = fmaxf(m, logit_sh[c]);
        float s = 0.f;
        for (int c = 0; c < NC; ++c) s += __expf(logit_sh[c] - m);
        lse_sh = m + logf(s);
    }
    __syncthreads();
    if (tid < NC) out[(size_t)b * NC + tid] = logit_sh[tid] - lse_sh;
}

// ============================ launch =======================================
extern "C" void kernel_launch(void* const* d_in, const int* in_sizes, int n_in,
                              void* d_out, int out_size, void* d_ws, size_t ws_size,
                              hipStream_t stream)
{
    const int*   x     = (const int*)d_in[0];
    const float* emb   = (const float*)d_in[1];
    const float* wWf   = (const float*)d_in[2];
    const float* wbif  = (const float*)d_in[3];
    const float* wbhf  = (const float*)d_in[4];
    const float* wWb   = (const float*)d_in[5];
    const float* wbib  = (const float*)d_in[6];
    const float* wbhb  = (const float*)d_in[7];
    const float* waW   = (const float*)d_in[8];
    const float* wab   = (const float*)d_in[9];
    const float* wactx = (const float*)d_in[10];
    const float* sWf   = (const float*)d_in[11];
    const float* sbif  = (const float*)d_in[12];
    const float* sbhf  = (const float*)d_in[13];
    const float* sWb   = (const float*)d_in[14];
    const float* sbib  = (const float*)d_in[15];
    const float* sbhb  = (const float*)d_in[16];
    const float* saW   = (const float*)d_in[17];
    const float* sab   = (const float*)d_in[18];
    const float* sactx = (const float*)d_in[19];
    const float* fcW   = (const float*)d_in[20];
    const float* fcb   = (const float*)d_in[21];
    float* out = (float*)d_out;

    if (ws_size < WS_NEED) {
        float* svec = (float*)d_ws;
        word_kernel_f32<<<NB * NS, 256, 0, stream>>>(
            x, emb, wWf, wbif, wbhf, wWb, wbib, wbhb, waW, wab, wactx, svec);
        sent_kernel_f32<<<NB, 256, 0, stream>>>(
            svec, sWf, sbif, sbhf, sWb, sbib, sbhb, saW, sab, sactx, fcW, fcb, out);
        return;
    }

    char* ws = (char*)d_ws;
    unsigned short* svec = (unsigned short*)(ws + OFF_SV);
    unsigned short* dvec = (unsigned short*)(ws + OFF_DV);

    pack_kernel<<<38, 256, 0, stream>>>(
        wWf, wbif, wbhf, wWb, wbib, wbhb, waW, wab, wactx,
        sWf, sbif, sbhf, sWb, sbib, sbhb, saW, sab, sactx, ws);

    // word stage: 5120 sentences / 2 per block (256 thr, 2 waves/sentence)
    han_kernel<true><<<NB * NS / 2, 256, 0, stream>>>(
        x, emb, ws, NW, svec);

    // sentence stage: 128 docs / 2 per block
    han_kernel<false><<<NB / 2, 256, 0, stream>>>(
        nullptr, svec, ws + 19ull * BBn, NS, dvec);

    cls_kernel<<<NB, 64, 0, stream>>>(dvec, fcW, fcb, out);
}